// Round 2
// baseline (262.117 us; speedup 1.0000x reference)
//
#include <hip/hip_runtime.h>
#include <hip/hip_bf16.h>

#define NB 8
#define NC 256
#define NHW 1024

// ---------------- GroupNorm: one block per (group, batch) ----------------
__global__ __launch_bounds__(256) void gn_kernel(
    const float* __restrict__ x, const float* __restrict__ gw,
    const float* __restrict__ gb, float* __restrict__ xn)
{
    const int g = blockIdx.x, b = blockIdx.y, t = threadIdx.x;
    const size_t base = ((size_t)b * NC + g * 8) * NHW;
    const float4* xi = (const float4*)(x + base);
    float4* xo = (float4*)(xn + base);
    float4 v[8];
    float sum = 0.f, sq = 0.f;
#pragma unroll
    for (int i = 0; i < 8; ++i) {
        v[i] = xi[t + i * 256];
        sum += v[i].x + v[i].y + v[i].z + v[i].w;
        sq += v[i].x * v[i].x + v[i].y * v[i].y + v[i].z * v[i].z + v[i].w * v[i].w;
    }
    const int lane = t & 63, w = t >> 6;
#pragma unroll
    for (int o = 32; o > 0; o >>= 1) {
        sum += __shfl_down(sum, o, 64);
        sq += __shfl_down(sq, o, 64);
    }
    __shared__ float rs[4][2];
    __shared__ float stats[2];
    if (lane == 0) { rs[w][0] = sum; rs[w][1] = sq; }
    __syncthreads();
    if (t == 0) {
        float S = rs[0][0] + rs[1][0] + rs[2][0] + rs[3][0];
        float Q = rs[0][1] + rs[1][1] + rs[2][1] + rs[3][1];
        float mu = S * (1.f / 8192.f);
        float var = Q * (1.f / 8192.f) - mu * mu;
        stats[0] = mu;
        stats[1] = rsqrtf(var + 1e-5f);
    }
    __syncthreads();
    const float mu = stats[0], ri = stats[1];
#pragma unroll
    for (int i = 0; i < 8; ++i) {
        const float sc = gw[g * 8 + i] * ri;
        const float off = gb[g * 8 + i] - mu * sc;
        float4 o;
        o.x = v[i].x * sc + off;
        o.y = v[i].y * sc + off;
        o.z = v[i].z * sc + off;
        o.w = v[i].w * sc + off;
        xo[t + i * 256] = o;
    }
}

// ---------------- fp32 GEMM: Y[b] = W[MxK] * X[b][KxN] + bias (+res) ----------------
// K=256, N=1024. 64x64 tile, BK=16, 4x4 micro-tile per thread.
template<int M, bool RES>
__global__ __launch_bounds__(256) void gemm_kernel(
    const float* __restrict__ W, const float* __restrict__ X,
    const float* __restrict__ bias, const float* __restrict__ res,
    float* __restrict__ Y)
{
    constexpr int K = 256, N = 1024, BK = 16, LD = 68;
    __shared__ float Ws[BK][LD];
    __shared__ float Xs[BK][LD];
    const int b = blockIdx.z, m0 = blockIdx.y * 64, n0 = blockIdx.x * 64;
    const int t = threadIdx.x;
    const int tm = t >> 4, tn = t & 15;
    const int wm = t >> 2, wk = (t & 3) << 2;
    const int xk = t >> 4, xnn = (t & 15) << 2;
    const float* Xb = X + (size_t)b * K * N;
    float acc[4][4] = {};
    for (int k0 = 0; k0 < K; k0 += BK) {
        const float4 wv = *(const float4*)&W[(size_t)(m0 + wm) * K + k0 + wk];
        const float4 xv = *(const float4*)&Xb[(size_t)(k0 + xk) * N + n0 + xnn];
        __syncthreads();
        Ws[wk + 0][wm] = wv.x;
        Ws[wk + 1][wm] = wv.y;
        Ws[wk + 2][wm] = wv.z;
        Ws[wk + 3][wm] = wv.w;
        *(float4*)&Xs[xk][xnn] = xv;
        __syncthreads();
#pragma unroll
        for (int kk = 0; kk < BK; ++kk) {
            const float4 a = *(const float4*)&Ws[kk][tm << 2];
            const float4 bb = *(const float4*)&Xs[kk][tn << 2];
            acc[0][0] += a.x * bb.x; acc[0][1] += a.x * bb.y; acc[0][2] += a.x * bb.z; acc[0][3] += a.x * bb.w;
            acc[1][0] += a.y * bb.x; acc[1][1] += a.y * bb.y; acc[1][2] += a.y * bb.z; acc[1][3] += a.y * bb.w;
            acc[2][0] += a.z * bb.x; acc[2][1] += a.z * bb.y; acc[2][2] += a.z * bb.z; acc[2][3] += a.z * bb.w;
            acc[3][0] += a.w * bb.x; acc[3][1] += a.w * bb.y; acc[3][2] += a.w * bb.z; acc[3][3] += a.w * bb.w;
        }
    }
#pragma unroll
    for (int i = 0; i < 4; ++i) {
        const int m = m0 + (tm << 2) + i;
        const float bs = bias[m];
        const size_t idx = ((size_t)b * M + m) * N + n0 + (tn << 2);
        float4 o;
        o.x = acc[i][0] + bs; o.y = acc[i][1] + bs; o.z = acc[i][2] + bs; o.w = acc[i][3] + bs;
        if (RES) {
            const float4 r = *(const float4*)&res[idx];
            o.x += r.x; o.y += r.y; o.z += r.z; o.w += r.w;
        }
        *(float4*)&Y[idx] = o;
    }
}

// ---------------- Flash attention ----------------
// qkv layout: [b][768][1024]; q ch = h*32+d, k ch = 256+h*32+d, v ch = 512+h*32+d
// Output layout (torch raw reshape): ao[b][h*32 + i/32][(i%32)*32 + d]
// grid: (16 row-tiles of 64, 64 bh). block 256 = 4 waves.
// lane = row-within-tile; each wave takes a disjoint j-quarter of each K/V tile.
__global__ __launch_bounds__(256) void attn_kernel(
    const float* __restrict__ qkv, float* __restrict__ ao)
{
    constexpr int LDK = 36;           // 32 + 4 pad, keeps float4 rows 16B-aligned
    constexpr int VOFF = 128 * LDK;   // 4608
    __shared__ float smem[2 * 128 * LDK];  // 9216 floats: K tile + V tile; reused for merge
    const int bh = blockIdx.y;
    const int b = bh >> 3, h = bh & 7;
    const int t = threadIdx.x;
    const int lane = t & 63, wave = t >> 6;
    const int row = blockIdx.x * 64 + lane;
    const size_t qb = ((size_t)b * 768 + h * 32) * 1024;
    float qreg[32];
#pragma unroll
    for (int d = 0; d < 32; ++d)
        qreg[d] = qkv[qb + (size_t)d * 1024 + row] * 0.17677669529663687f;

    float m = -1e30f, lsum = 0.f;
    float acc[32] = {};

    const int sd = t >> 3;          // staging: d-row
    const int sj = (t & 7) << 2;    // staging: j offset within 32-j chunk
    const float* kgb = qkv + ((size_t)b * 768 + 256 + h * 32 + sd) * 1024;
    const float* vgb = kgb + 256 * 1024;
    const int jlo = wave * 32;

    for (int T = 0; T < 8; ++T) {
        __syncthreads();
        const int jt = T * 128;
#pragma unroll
        for (int q4 = 0; q4 < 4; ++q4) {
            const int jj = sj + q4 * 32;
            const float4 kv = *(const float4*)(kgb + jt + jj);
            const float4 vv = *(const float4*)(vgb + jt + jj);
            smem[(jj + 0) * LDK + sd] = kv.x;
            smem[(jj + 1) * LDK + sd] = kv.y;
            smem[(jj + 2) * LDK + sd] = kv.z;
            smem[(jj + 3) * LDK + sd] = kv.w;
            smem[VOFF + (jj + 0) * LDK + sd] = vv.x;
            smem[VOFF + (jj + 1) * LDK + sd] = vv.y;
            smem[VOFF + (jj + 2) * LDK + sd] = vv.z;
            smem[VOFF + (jj + 3) * LDK + sd] = vv.w;
        }
        __syncthreads();
        for (int jj = jlo; jj < jlo + 32; ++jj) {
            const float4* kp = (const float4*)&smem[jj * LDK];
            float s0 = 0.f, s1 = 0.f, s2 = 0.f, s3 = 0.f;
#pragma unroll
            for (int dd = 0; dd < 8; ++dd) {
                const float4 k4 = kp[dd];
                s0 += qreg[dd * 4 + 0] * k4.x;
                s1 += qreg[dd * 4 + 1] * k4.y;
                s2 += qreg[dd * 4 + 2] * k4.z;
                s3 += qreg[dd * 4 + 3] * k4.w;
            }
            const float s = (s0 + s1) + (s2 + s3);
            const float4* vp = (const float4*)&smem[VOFF + jj * LDK];
            if (s <= m) {
                const float p = __expf(s - m);
                lsum += p;
#pragma unroll
                for (int dd = 0; dd < 8; ++dd) {
                    const float4 v4 = vp[dd];
                    acc[dd * 4 + 0] += p * v4.x;
                    acc[dd * 4 + 1] += p * v4.y;
                    acc[dd * 4 + 2] += p * v4.z;
                    acc[dd * 4 + 3] += p * v4.w;
                }
            } else {
                const float cor = __expf(m - s);
                m = s;
                lsum = lsum * cor + 1.f;
#pragma unroll
                for (int dd = 0; dd < 8; ++dd) {
                    const float4 v4 = vp[dd];
                    acc[dd * 4 + 0] = acc[dd * 4 + 0] * cor + v4.x;
                    acc[dd * 4 + 1] = acc[dd * 4 + 1] * cor + v4.y;
                    acc[dd * 4 + 2] = acc[dd * 4 + 2] * cor + v4.z;
                    acc[dd * 4 + 3] = acc[dd * 4 + 3] * cor + v4.w;
                }
            }
        }
    }

    // merge the 4 per-wave partial softmax states through LDS
    __syncthreads();
    float* st = smem + (size_t)(wave * 64 + lane) * 34;
    st[0] = m;
    st[1] = lsum;
#pragma unroll
    for (int d = 0; d < 32; ++d) st[2 + d] = acc[d];
    __syncthreads();
    if (wave == 0) {
        float mm = -1e30f;
#pragma unroll
        for (int w = 0; w < 4; ++w)
            mm = fmaxf(mm, smem[(w * 64 + lane) * 34]);
        float L = 0.f;
        float oacc[32] = {};
#pragma unroll
        for (int w = 0; w < 4; ++w) {
            const float* p = smem + (w * 64 + lane) * 34;
            const float c = __expf(p[0] - mm);
            L += c * p[1];
#pragma unroll
            for (int d = 0; d < 32; ++d) oacc[d] += c * p[2 + d];
        }
        const float inv = 1.f / L;
        const int cOut = h * 32 + (row >> 5);
        const int pOut = (row & 31) << 5;
        float* og = ao + ((size_t)b * 256 + cOut) * 1024 + pOut;
#pragma unroll
        for (int d4 = 0; d4 < 8; ++d4) {
            float4 o;
            o.x = oacc[d4 * 4 + 0] * inv;
            o.y = oacc[d4 * 4 + 1] * inv;
            o.z = oacc[d4 * 4 + 2] * inv;
            o.w = oacc[d4 * 4 + 3] * inv;
            ((float4*)og)[d4] = o;
        }
    }
}

extern "C" void kernel_launch(void* const* d_in, const int* in_sizes, int n_in,
                              void* d_out, int out_size, void* d_ws, size_t ws_size,
                              hipStream_t stream) {
    const float* x      = (const float*)d_in[0];
    const float* norm_w = (const float*)d_in[1];
    const float* norm_b = (const float*)d_in[2];
    const float* qkv_w  = (const float*)d_in[3];
    const float* qkv_b  = (const float*)d_in[4];
    const float* out_w  = (const float*)d_in[5];
    const float* out_b  = (const float*)d_in[6];
    float* out = (float*)d_out;

    float* xn  = (float*)d_ws;                       // 2M floats (8 MB)
    float* qkv = xn + (size_t)NB * NC * NHW;         // 6M floats (24 MB)
    float* ao  = qkv + (size_t)NB * 3 * NC * NHW;    // 2M floats (8 MB)

    gn_kernel<<<dim3(32, NB), 256, 0, stream>>>(x, norm_w, norm_b, xn);
    gemm_kernel<768, false><<<dim3(16, 12, NB), 256, 0, stream>>>(qkv_w, xn, qkv_b, nullptr, qkv);
    attn_kernel<<<dim3(16, 64), 256, 0, stream>>>(qkv, ao);
    gemm_kernel<256, true><<<dim3(16, 4, NB), 256, 0, stream>>>(out_w, ao, out_b, x, out);
}

// Round 4
// 101.151 us; speedup vs baseline: 2.5913x; 2.5913x over previous
//
#include <hip/hip_runtime.h>
#include <hip/hip_bf16.h>

#define NB 8
#define NC 256
#define NHW 1024

using f16x8  = __attribute__((ext_vector_type(8))) _Float16;
using f32x16 = __attribute__((ext_vector_type(16))) float;
using u32x4  = __attribute__((ext_vector_type(4))) unsigned int;

static __device__ inline unsigned short f2h(float f) {
    _Float16 h = (_Float16)f;
    return __builtin_bit_cast(unsigned short, h);
}
static __device__ inline unsigned pk2(float a, float b) {
    auto r = __builtin_amdgcn_cvt_pkrtz(a, b);   // __fp16 ext_vector_type(2)
    return __builtin_bit_cast(unsigned, r);
}
static __device__ inline float vmax16(const f32x16& v) {
    float m0 = fmaxf(fmaxf(v[0], v[1]), fmaxf(v[2], v[3]));
    float m1 = fmaxf(fmaxf(v[4], v[5]), fmaxf(v[6], v[7]));
    float m2 = fmaxf(fmaxf(v[8], v[9]), fmaxf(v[10], v[11]));
    float m3 = fmaxf(fmaxf(v[12], v[13]), fmaxf(v[14], v[15]));
    return fmaxf(fmaxf(m0, m1), fmaxf(m2, m3));
}
static __device__ inline float vsum16(const f32x16& v) {
    float s0 = (v[0] + v[1]) + (v[2] + v[3]);
    float s1 = (v[4] + v[5]) + (v[6] + v[7]);
    float s2 = (v[8] + v[9]) + (v[10] + v[11]);
    float s3 = (v[12] + v[13]) + (v[14] + v[15]);
    return (s0 + s1) + (s2 + s3);
}
// Assemble PV A-fragment (P[row=i=lane&31][k=j], k=8h+t) from 8 exp'd S regs.
// Reg r of a 32x32 accumulator holds j=(r&3)+8*(r>>2)+4h within its 16-j half.
template<int B>
static __device__ inline f16x8 packP(const f32x16& p, const int h) {
    unsigned u0 = pk2(p[B + 0], p[B + 1]);
    unsigned u1 = pk2(p[B + 2], p[B + 3]);
    unsigned u2 = pk2(p[B + 4], p[B + 5]);
    unsigned u3 = pk2(p[B + 6], p[B + 7]);
    unsigned pu0 = __shfl_xor(u0, 32);
    unsigned pu1 = __shfl_xor(u1, 32);
    unsigned pu2 = __shfl_xor(u2, 32);
    unsigned pu3 = __shfl_xor(u3, 32);
    u32x4 w;
    w[0] = h ? pu2 : u0;
    w[1] = h ? pu3 : u1;
    w[2] = h ? u2 : pu0;
    w[3] = h ? u3 : pu1;
    return __builtin_bit_cast(f16x8, w);
}

// ---------------- GroupNorm ----------------
__global__ __launch_bounds__(256) void gn_kernel(
    const float* __restrict__ x, const float* __restrict__ gw,
    const float* __restrict__ gb, float* __restrict__ xn)
{
    const int g = blockIdx.x, b = blockIdx.y, t = threadIdx.x;
    const size_t base = ((size_t)b * NC + g * 8) * NHW;
    const float4* xi = (const float4*)(x + base);
    float4* xo = (float4*)(xn + base);
    float4 v[8];
    float sum = 0.f, sq = 0.f;
#pragma unroll
    for (int i = 0; i < 8; ++i) {
        v[i] = xi[t + i * 256];
        sum += v[i].x + v[i].y + v[i].z + v[i].w;
        sq += v[i].x * v[i].x + v[i].y * v[i].y + v[i].z * v[i].z + v[i].w * v[i].w;
    }
    const int lane = t & 63, w = t >> 6;
#pragma unroll
    for (int o = 32; o > 0; o >>= 1) {
        sum += __shfl_down(sum, o, 64);
        sq += __shfl_down(sq, o, 64);
    }
    __shared__ float rs[4][2];
    __shared__ float stats[2];
    if (lane == 0) { rs[w][0] = sum; rs[w][1] = sq; }
    __syncthreads();
    if (t == 0) {
        float S = rs[0][0] + rs[1][0] + rs[2][0] + rs[3][0];
        float Q = rs[0][1] + rs[1][1] + rs[2][1] + rs[3][1];
        float mu = S * (1.f / 8192.f);
        float var = Q * (1.f / 8192.f) - mu * mu;
        stats[0] = mu;
        stats[1] = rsqrtf(var + 1e-5f);
    }
    __syncthreads();
    const float mu = stats[0], ri = stats[1];
#pragma unroll
    for (int i = 0; i < 8; ++i) {
        const float sc = gw[g * 8 + i] * ri;
        const float off = gb[g * 8 + i] - mu * sc;
        float4 o;
        o.x = v[i].x * sc + off;
        o.y = v[i].y * sc + off;
        o.z = v[i].z * sc + off;
        o.w = v[i].w * sc + off;
        xo[t + i * 256] = o;
    }
}

// ---------------- QKV GEMM (fp32 math) with f16 transposing epilogue ----------------
// Writes qT[bh][i][d] (scaled), kT[bh][j][d], vN[bh][d][j], all f16.
__global__ __launch_bounds__(256) void qkv_gemm_kernel(
    const float* __restrict__ W, const float* __restrict__ X,
    const float* __restrict__ bias,
    unsigned short* __restrict__ qT, unsigned short* __restrict__ kT,
    unsigned short* __restrict__ vN)
{
    constexpr int K = 256, N = 1024, BK = 16, LD = 68;
    __shared__ float Ws[BK][LD];
    __shared__ float Xs[BK][LD];
    const int b = blockIdx.z, m0 = blockIdx.y * 64, n0 = blockIdx.x * 64;
    const int t = threadIdx.x;
    const int tm = t >> 4, tn = t & 15;
    const int wm = t >> 2, wk = (t & 3) << 2;
    const int xk = t >> 4, xnn = (t & 15) << 2;
    const float* Xb = X + (size_t)b * K * N;
    float acc[4][4] = {};
    for (int k0 = 0; k0 < K; k0 += BK) {
        const float4 wv = *(const float4*)&W[(size_t)(m0 + wm) * K + k0 + wk];
        const float4 xv = *(const float4*)&Xb[(size_t)(k0 + xk) * N + n0 + xnn];
        __syncthreads();
        Ws[wk + 0][wm] = wv.x;
        Ws[wk + 1][wm] = wv.y;
        Ws[wk + 2][wm] = wv.z;
        Ws[wk + 3][wm] = wv.w;
        *(float4*)&Xs[xk][xnn] = xv;
        __syncthreads();
#pragma unroll
        for (int kk = 0; kk < BK; ++kk) {
            const float4 a = *(const float4*)&Ws[kk][tm << 2];
            const float4 bb = *(const float4*)&Xs[kk][tn << 2];
            acc[0][0] += a.x * bb.x; acc[0][1] += a.x * bb.y; acc[0][2] += a.x * bb.z; acc[0][3] += a.x * bb.w;
            acc[1][0] += a.y * bb.x; acc[1][1] += a.y * bb.y; acc[1][2] += a.y * bb.z; acc[1][3] += a.y * bb.w;
            acc[2][0] += a.z * bb.x; acc[2][1] += a.z * bb.y; acc[2][2] += a.z * bb.z; acc[2][3] += a.z * bb.w;
            acc[3][0] += a.w * bb.x; acc[3][1] += a.w * bb.y; acc[3][2] += a.w * bb.z; acc[3][3] += a.w * bb.w;
        }
    }
    const int type = blockIdx.y >> 2;               // 0=Q, 1=K, 2=V
    const int mloc = (m0 & 255) + (tm << 2);        // channel within 256
    const int headg = mloc >> 5;
    const int bh = b * 8 + headg;
    const int d0 = mloc & 31;
    const int n0j = n0 + (tn << 2);
    float bs[4];
#pragma unroll
    for (int i = 0; i < 4; ++i) bs[i] = bias[m0 + (tm << 2) + i];
    if (type == 2) {
#pragma unroll
        for (int i = 0; i < 4; ++i) {
            ushort4 w;
            w.x = f2h(acc[i][0] + bs[i]);
            w.y = f2h(acc[i][1] + bs[i]);
            w.z = f2h(acc[i][2] + bs[i]);
            w.w = f2h(acc[i][3] + bs[i]);
            *(ushort4*)&vN[((size_t)bh * 32 + d0 + i) * 1024 + n0j] = w;
        }
    } else {
        const float sc = (type == 0) ? 0.17677669529663687f : 1.f;
        unsigned short* dst = (type == 0) ? qT : kT;
#pragma unroll
        for (int nn = 0; nn < 4; ++nn) {
            ushort4 w;
            w.x = f2h((acc[0][nn] + bs[0]) * sc);
            w.y = f2h((acc[1][nn] + bs[1]) * sc);
            w.z = f2h((acc[2][nn] + bs[2]) * sc);
            w.w = f2h((acc[3][nn] + bs[3]) * sc);
            *(ushort4*)&dst[((size_t)bh * 1024 + n0j + nn) * 32 + d0] = w;
        }
    }
}

// ---------------- fp32 GEMM for the output projection (+bias+residual) ----------------
__global__ __launch_bounds__(256) void out_gemm_kernel(
    const float* __restrict__ W, const float* __restrict__ X,
    const float* __restrict__ bias, const float* __restrict__ res,
    float* __restrict__ Y)
{
    constexpr int K = 256, N = 1024, BK = 16, LD = 68, M = 256;
    __shared__ float Ws[BK][LD];
    __shared__ float Xs[BK][LD];
    const int b = blockIdx.z, m0 = blockIdx.y * 64, n0 = blockIdx.x * 64;
    const int t = threadIdx.x;
    const int tm = t >> 4, tn = t & 15;
    const int wm = t >> 2, wk = (t & 3) << 2;
    const int xk = t >> 4, xnn = (t & 15) << 2;
    const float* Xb = X + (size_t)b * K * N;
    float acc[4][4] = {};
    for (int k0 = 0; k0 < K; k0 += BK) {
        const float4 wv = *(const float4*)&W[(size_t)(m0 + wm) * K + k0 + wk];
        const float4 xv = *(const float4*)&Xb[(size_t)(k0 + xk) * N + n0 + xnn];
        __syncthreads();
        Ws[wk + 0][wm] = wv.x;
        Ws[wk + 1][wm] = wv.y;
        Ws[wk + 2][wm] = wv.z;
        Ws[wk + 3][wm] = wv.w;
        *(float4*)&Xs[xk][xnn] = xv;
        __syncthreads();
#pragma unroll
        for (int kk = 0; kk < BK; ++kk) {
            const float4 a = *(const float4*)&Ws[kk][tm << 2];
            const float4 bb = *(const float4*)&Xs[kk][tn << 2];
            acc[0][0] += a.x * bb.x; acc[0][1] += a.x * bb.y; acc[0][2] += a.x * bb.z; acc[0][3] += a.x * bb.w;
            acc[1][0] += a.y * bb.x; acc[1][1] += a.y * bb.y; acc[1][2] += a.y * bb.z; acc[1][3] += a.y * bb.w;
            acc[2][0] += a.z * bb.x; acc[2][1] += a.z * bb.y; acc[2][2] += a.z * bb.z; acc[2][3] += a.z * bb.w;
            acc[3][0] += a.w * bb.x; acc[3][1] += a.w * bb.y; acc[3][2] += a.w * bb.z; acc[3][3] += a.w * bb.w;
        }
    }
#pragma unroll
    for (int i = 0; i < 4; ++i) {
        const int m = m0 + (tm << 2) + i;
        const float bsv = bias[m];
        const size_t idx = ((size_t)b * M + m) * N + n0 + (tn << 2);
        const float4 r = *(const float4*)&res[idx];
        float4 o;
        o.x = acc[i][0] + bsv + r.x;
        o.y = acc[i][1] + bsv + r.y;
        o.z = acc[i][2] + bsv + r.z;
        o.w = acc[i][3] + bsv + r.w;
        *(float4*)&Y[idx] = o;
    }
}

// ---------------- MFMA flash attention ----------------
// grid (8 i-tiles of 128, 64 bh), 256 threads = 4 waves; wave w owns 32 q-rows.
// S^T = mfma(A=K^T[32j x 16d], B=Q[16d x 32i]): lane col = i = lane&31 (softmax lane-local).
// PV: out = mfma(A=P[32i x 16j], B=V^T[16j x 32d]).
__global__ __launch_bounds__(256) void attn_mfma_kernel(
    const unsigned short* __restrict__ qT, const unsigned short* __restrict__ kT,
    const unsigned short* __restrict__ vN, float* __restrict__ ao)
{
    __shared__ __align__(16) unsigned short Ks[64 * 40];  // K^T tile, 80 B rows (5j%8 quad spread)
    __shared__ __align__(16) unsigned short Vs[32 * 72];  // V tile,  144 B rows (9d%8 quad spread)
    const int bh = blockIdx.y;
    const int b = bh >> 3, head = bh & 7;
    const int t = threadIdx.x;
    const int lane = t & 63;
    const int w = t >> 6;
    const int l31 = lane & 31;
    const int h = lane >> 5;
    const int ibase = blockIdx.x * 128 + w * 32;

    // Q fragments, held for the whole j-loop. B-frag: col=i=lane&31, k=d=8h+t.
    const unsigned short* qrow = qT + ((size_t)bh * 1024 + ibase + l31) * 32;
    const f16x8 qf0 = *(const f16x8*)(qrow + h * 8);        // d 0..15
    const f16x8 qf1 = *(const f16x8*)(qrow + 16 + h * 8);   // d 16..31

    f32x16 out = {};
    float m = -1e30f, lsum = 0.f;

    const int kj = t >> 2, kq = t & 3;
    const unsigned short* kg = kT + ((size_t)bh * 1024 + kj) * 32 + kq * 8;
    const int vd = t >> 3, vq = t & 7;
    const unsigned short* vg = vN + ((size_t)bh * 32 + vd) * 1024 + vq * 8;

    for (int T = 0; T < 16; ++T) {
        __syncthreads();
        *(float4*)&Ks[kj * 40 + kq * 8] = *(const float4*)(kg + (size_t)T * 2048);
        *(float4*)&Vs[vd * 72 + vq * 8] = *(const float4*)(vg + T * 64);
        __syncthreads();

        // A-frags of K^T: row=j=lane&31 (per 32-j set), k=d=8h+t
        const f16x8 kf00 = *(const f16x8*)&Ks[l31 * 40 + h * 8];
        const f16x8 kf01 = *(const f16x8*)&Ks[l31 * 40 + 16 + h * 8];
        const f16x8 kf10 = *(const f16x8*)&Ks[(32 + l31) * 40 + h * 8];
        const f16x8 kf11 = *(const f16x8*)&Ks[(32 + l31) * 40 + 16 + h * 8];
        f32x16 sA = {}, sB = {};
        sA = __builtin_amdgcn_mfma_f32_32x32x16_f16(kf00, qf0, sA, 0, 0, 0);
        sA = __builtin_amdgcn_mfma_f32_32x32x16_f16(kf01, qf1, sA, 0, 0, 0);
        sB = __builtin_amdgcn_mfma_f32_32x32x16_f16(kf10, qf0, sB, 0, 0, 0);
        sB = __builtin_amdgcn_mfma_f32_32x32x16_f16(kf11, qf1, sB, 0, 0, 0);

        // per-column (i) max over all 64 j of this chunk
        float mt = fmaxf(vmax16(sA), vmax16(sB));
        mt = fmaxf(mt, __shfl_xor(mt, 32));
        if (!__all(mt <= m + 8.f)) {          // defer-max (T13)
            const float mn = fmaxf(m, mt);
            const float cor = __expf(m - mn);
            m = mn;
            lsum *= cor;
#pragma unroll
            for (int r = 0; r < 16; ++r) {
                const int src = (r & 3) + 8 * (r >> 2) + 4 * h;  // lane holding row i's cor
                out[r] *= __shfl(cor, src);
            }
        }
#pragma unroll
        for (int r = 0; r < 16; ++r) {
            sA[r] = __expf(sA[r] - m);
            sB[r] = __expf(sB[r] - m);
        }
        float ps = vsum16(sA) + vsum16(sB);
        ps += __shfl_xor(ps, 32);
        lsum += ps;

        const f16x8 pf0 = packP<0>(sA, h);
        const f16x8 pf1 = packP<8>(sA, h);
        const f16x8 pf2 = packP<0>(sB, h);
        const f16x8 pf3 = packP<8>(sB, h);
        // V^T B-frags: col=d=lane&31, k=j=8h+t within each 16-j chunk
        const f16x8 vf0 = *(const f16x8*)&Vs[l31 * 72 + h * 8];
        const f16x8 vf1 = *(const f16x8*)&Vs[l31 * 72 + 16 + h * 8];
        const f16x8 vf2 = *(const f16x8*)&Vs[l31 * 72 + 32 + h * 8];
        const f16x8 vf3 = *(const f16x8*)&Vs[l31 * 72 + 48 + h * 8];
        out = __builtin_amdgcn_mfma_f32_32x32x16_f16(pf0, vf0, out, 0, 0, 0);
        out = __builtin_amdgcn_mfma_f32_32x32x16_f16(pf1, vf1, out, 0, 0, 0);
        out = __builtin_amdgcn_mfma_f32_32x32x16_f16(pf2, vf2, out, 0, 0, 0);
        out = __builtin_amdgcn_mfma_f32_32x32x16_f16(pf3, vf3, out, 0, 0, 0);
    }

    // epilogue: scale rows by 1/lsum (redistribute per-column state to out rows), write ao
    const float linv = 1.f / lsum;
    const int cOut = b * 256 + head * 32 + blockIdx.x * 4 + w;
    float* og = ao + (size_t)cOut * 1024 + l31;
#pragma unroll
    for (int r = 0; r < 16; ++r) {
        const int crow = (r & 3) + 8 * (r >> 2) + 4 * h;
        const float sc = __shfl(linv, crow);
        og[crow * 32] = out[r] * sc;
    }
}

extern "C" void kernel_launch(void* const* d_in, const int* in_sizes, int n_in,
                              void* d_out, int out_size, void* d_ws, size_t ws_size,
                              hipStream_t stream) {
    const float* x      = (const float*)d_in[0];
    const float* norm_w = (const float*)d_in[1];
    const float* norm_b = (const float*)d_in[2];
    const float* qkv_w  = (const float*)d_in[3];
    const float* qkv_b  = (const float*)d_in[4];
    const float* out_w  = (const float*)d_in[5];
    const float* out_b  = (const float*)d_in[6];
    float* out = (float*)d_out;

    float* xn = (float*)d_ws;                                  // 8 MB
    float* ao = xn + (size_t)NB * NC * NHW;                    // 8 MB
    unsigned short* qT = (unsigned short*)(ao + (size_t)NB * NC * NHW);  // 4 MB
    unsigned short* kT = qT + (size_t)64 * 1024 * 32;          // 4 MB
    unsigned short* vN = kT + (size_t)64 * 1024 * 32;          // 4 MB

    gn_kernel<<<dim3(32, NB), 256, 0, stream>>>(x, norm_w, norm_b, xn);
    qkv_gemm_kernel<<<dim3(16, 12, NB), 256, 0, stream>>>(qkv_w, xn, qkv_b, qT, kT, vN);
    attn_mfma_kernel<<<dim3(8, 64), 256, 0, stream>>>(qT, kT, vN, ao);
    out_gemm_kernel<<<dim3(16, 4, NB), 256, 0, stream>>>(out_w, ao, out_b, x, out);
}

// Round 5
// 86.309 us; speedup vs baseline: 3.0370x; 1.1720x over previous
//
#include <hip/hip_runtime.h>
#include <hip/hip_bf16.h>

#define NB 8
#define NC 256
#define NHW 1024

typedef unsigned short u16;
using f16x8  = __attribute__((ext_vector_type(8))) _Float16;
using f32x16 = __attribute__((ext_vector_type(16))) float;
using u32x4  = __attribute__((ext_vector_type(4))) unsigned int;
using u16x8  = __attribute__((ext_vector_type(8))) unsigned short;

static __device__ inline u16 f2h(float f) {
    _Float16 h = (_Float16)f;
    return __builtin_bit_cast(u16, h);
}
static __device__ inline float h2f(u16 u) {
    return (float)__builtin_bit_cast(_Float16, u);
}
static __device__ inline unsigned packh2(float a, float b) {
    return (unsigned)f2h(a) | ((unsigned)f2h(b) << 16);
}
static __device__ inline unsigned pk2(float a, float b) {
    auto r = __builtin_amdgcn_cvt_pkrtz(a, b);
    return __builtin_bit_cast(unsigned, r);
}
static __device__ inline float vmax16(const f32x16& v) {
    float m0 = fmaxf(fmaxf(v[0], v[1]), fmaxf(v[2], v[3]));
    float m1 = fmaxf(fmaxf(v[4], v[5]), fmaxf(v[6], v[7]));
    float m2 = fmaxf(fmaxf(v[8], v[9]), fmaxf(v[10], v[11]));
    float m3 = fmaxf(fmaxf(v[12], v[13]), fmaxf(v[14], v[15]));
    return fmaxf(fmaxf(m0, m1), fmaxf(m2, m3));
}
static __device__ inline float vsum16(const f32x16& v) {
    float s0 = (v[0] + v[1]) + (v[2] + v[3]);
    float s1 = (v[4] + v[5]) + (v[6] + v[7]);
    float s2 = (v[8] + v[9]) + (v[10] + v[11]);
    float s3 = (v[12] + v[13]) + (v[14] + v[15]);
    return (s0 + s1) + (s2 + s3);
}
template<int B>
static __device__ inline f16x8 packP(const f32x16& p, const int h) {
    unsigned u0 = pk2(p[B + 0], p[B + 1]);
    unsigned u1 = pk2(p[B + 2], p[B + 3]);
    unsigned u2 = pk2(p[B + 4], p[B + 5]);
    unsigned u3 = pk2(p[B + 6], p[B + 7]);
    unsigned pu0 = __shfl_xor(u0, 32);
    unsigned pu1 = __shfl_xor(u1, 32);
    unsigned pu2 = __shfl_xor(u2, 32);
    unsigned pu3 = __shfl_xor(u3, 32);
    u32x4 w;
    w[0] = h ? pu2 : u0;
    w[1] = h ? pu3 : u1;
    w[2] = h ? u2 : pu0;
    w[3] = h ? u3 : pu1;
    return __builtin_bit_cast(f16x8, w);
}

// ---------------- GroupNorm stats only ----------------
__global__ __launch_bounds__(256) void gn_stats_kernel(
    const float* __restrict__ x, float2* __restrict__ stats)
{
    const int g = blockIdx.x, b = blockIdx.y, t = threadIdx.x;
    const size_t base = ((size_t)b * NC + g * 8) * NHW;
    const float4* xi = (const float4*)(x + base);
    float sum = 0.f, sq = 0.f;
#pragma unroll
    for (int i = 0; i < 8; ++i) {
        float4 v = xi[t + i * 256];
        sum += v.x + v.y + v.z + v.w;
        sq += v.x * v.x + v.y * v.y + v.z * v.z + v.w * v.w;
    }
    const int lane = t & 63, wv = t >> 6;
#pragma unroll
    for (int o = 32; o > 0; o >>= 1) {
        sum += __shfl_down(sum, o, 64);
        sq += __shfl_down(sq, o, 64);
    }
    __shared__ float rs[4][2];
    if (lane == 0) { rs[wv][0] = sum; rs[wv][1] = sq; }
    __syncthreads();
    if (t == 0) {
        float S = rs[0][0] + rs[1][0] + rs[2][0] + rs[3][0];
        float Q = rs[0][1] + rs[1][1] + rs[2][1] + rs[3][1];
        float mu = S * (1.f / 8192.f);
        float var = Q * (1.f / 8192.f) - mu * mu;
        stats[b * 32 + g] = make_float2(mu, rsqrtf(var + 1e-5f));
    }
}

// ---------------- weight split (fp32 -> f16 hi/lo), q rows pre-scaled ----------------
__global__ __launch_bounds__(256) void wsplit_kernel(
    const float* __restrict__ qkv_w, const float* __restrict__ out_w,
    u16* __restrict__ Wqh, u16* __restrict__ Wql,
    u16* __restrict__ Woh, u16* __restrict__ Wol)
{
    const int f4 = blockIdx.x * 256 + threadIdx.x;   // 0..65535
    float4 v;
    u16 *dhp, *dlp;
    int e;
    if (f4 < 49152) {
        e = f4 * 4;
        v = *(const float4*)&qkv_w[e];
        if ((e >> 8) < 256) {
            const float s = 0.17677669529663687f;
            v.x *= s; v.y *= s; v.z *= s; v.w *= s;
        }
        dhp = Wqh; dlp = Wql;
    } else {
        e = (f4 - 49152) * 4;
        v = *(const float4*)&out_w[e];
        dhp = Woh; dlp = Wol;
    }
    ushort4 hh, ll;
    hh.x = f2h(v.x); ll.x = f2h(v.x - h2f(hh.x));
    hh.y = f2h(v.y); ll.y = f2h(v.y - h2f(hh.y));
    hh.z = f2h(v.z); ll.z = f2h(v.z - h2f(hh.z));
    hh.w = f2h(v.w); ll.w = f2h(v.w - h2f(hh.w));
    *(ushort4*)&dhp[e] = hh;
    *(ushort4*)&dlp[e] = ll;
}

// ---------------- transpose + split (optionally fused GroupNorm) ----------------
// src [b][256][1024] fp32 -> dst hi/lo [b][1024][256] f16
template<bool NORM>
__global__ __launch_bounds__(256) void tsplit_kernel(
    const float* __restrict__ src, const float2* __restrict__ stats,
    const float* __restrict__ gw, const float* __restrict__ gb,
    u16* __restrict__ dh, u16* __restrict__ dl)
{
    __shared__ float lds[64][68];
    const int b = blockIdx.z;
    const int c0 = blockIdx.y * 64, hw0 = blockIdx.x * 64;
    const int t = threadIdx.x;
    const int cL = t >> 4, hwL = (t & 15) * 4;
#pragma unroll
    for (int i = 0; i < 4; ++i) {
        const int c = c0 + cL + i * 16;
        float4 v = *(const float4*)&src[((size_t)b * 256 + c) * 1024 + hw0 + hwL];
        if (NORM) {
            const float2 st = stats[b * 32 + (c >> 3)];
            const float sc = gw[c] * st.y;
            const float off = gb[c] - st.x * sc;
            v.x = v.x * sc + off; v.y = v.y * sc + off;
            v.z = v.z * sc + off; v.w = v.w * sc + off;
        }
        *(float4*)&lds[cL + i * 16][hwL] = v;
    }
    __syncthreads();
    const int lane = t & 63, w = t >> 6;
    const int hwR = lane, cq = w * 16;
    u16x8 H0, H1, L0, L1;
#pragma unroll
    for (int j = 0; j < 8; ++j) {
        float f = lds[cq + j][hwR];
        u16 hh = f2h(f);
        H0[j] = hh;
        L0[j] = f2h(f - h2f(hh));
        float f2 = lds[cq + 8 + j][hwR];
        u16 hh2 = f2h(f2);
        H1[j] = hh2;
        L1[j] = f2h(f2 - h2f(hh2));
    }
    const size_t o = ((size_t)b * 1024 + hw0 + hwR) * 256 + c0 + cq;
    *(u16x8*)&dh[o] = H0; *(u16x8*)&dh[o + 8] = H1;
    *(u16x8*)&dl[o] = L0; *(u16x8*)&dl[o + 8] = L1;
}

// ---------------- split-precision MFMA GEMM ----------------
// C[M x 1024] = W[M x 256] * B^T (B stored [b][n][k], k-contiguous) + bias
// block: 128m x 128n, 4 waves, each wave one 32m sub x 4 n-subs.
// A-frags from global (L2-resident), B staged in LDS.
// IS_QKV epilogue: write qT[bh][i][d], kT[bh][j][d], vN[bh][d][j] f16.
// else: Y = C + res (fp32).
template<bool IS_QKV>
__global__ __launch_bounds__(256) void mfma_gemm_kernel(
    const u16* __restrict__ Wh, const u16* __restrict__ Wl,
    const u16* __restrict__ Bh, const u16* __restrict__ Bl,
    const float* __restrict__ bias,
    u16* __restrict__ qT, u16* __restrict__ kT, u16* __restrict__ vN,
    const float* __restrict__ res, float* __restrict__ Y)
{
    __shared__ __align__(16) u16 sBh[128 * 40];
    __shared__ __align__(16) u16 sBl[128 * 40];
    const int b = blockIdx.z;
    const int m0 = blockIdx.y * 128, n0 = blockIdx.x * 128;
    const int t = threadIdx.x, w = t >> 6, lane = t & 63;
    const int l31 = lane & 31, h = lane >> 5;
    const int msub = m0 + w * 32;

    const u16* Bhb = Bh + ((size_t)b * 1024 + n0) * 256;
    const u16* Blb = Bl + ((size_t)b * 1024 + n0) * 256;
    const u16* War = Wh + (size_t)(msub + l31) * 256 + h * 8;
    const u16* Wbr = Wl + (size_t)(msub + l31) * 256 + h * 8;

    const float bscale = (IS_QKV && msub < 256) ? 0.17677669529663687f : 1.0f;
    f32x16 acc[4];
#pragma unroll
    for (int r = 0; r < 16; ++r) {
        const int crow = (r & 3) + 8 * (r >> 2) + 4 * h;
        const float bv = bias[msub + crow] * bscale;
        acc[0][r] = bv; acc[1][r] = bv; acc[2][r] = bv; acc[3][r] = bv;
    }

    const int sr = t >> 2, sq = t & 3;
    const size_t gb0 = (size_t)sr * 256 + sq * 8;

    for (int kc = 0; kc < 8; ++kc) {
        __syncthreads();
        const size_t g0 = gb0 + kc * 32;
        *(uint4*)&sBh[sr * 40 + sq * 8]        = *(const uint4*)&Bhb[g0];
        *(uint4*)&sBh[(sr + 64) * 40 + sq * 8] = *(const uint4*)&Bhb[g0 + 64 * 256];
        *(uint4*)&sBl[sr * 40 + sq * 8]        = *(const uint4*)&Blb[g0];
        *(uint4*)&sBl[(sr + 64) * 40 + sq * 8] = *(const uint4*)&Blb[g0 + 64 * 256];
        __syncthreads();
#pragma unroll
        for (int k16 = 0; k16 < 2; ++k16) {
            const f16x8 ah = *(const f16x8*)(War + kc * 32 + k16 * 16);
            const f16x8 al = *(const f16x8*)(Wbr + kc * 32 + k16 * 16);
#pragma unroll
            for (int ns = 0; ns < 4; ++ns) {
                const f16x8 bh = *(const f16x8*)&sBh[(ns * 32 + l31) * 40 + k16 * 16 + h * 8];
                const f16x8 bl = *(const f16x8*)&sBl[(ns * 32 + l31) * 40 + k16 * 16 + h * 8];
                acc[ns] = __builtin_amdgcn_mfma_f32_32x32x16_f16(ah, bh, acc[ns], 0, 0, 0);
                acc[ns] = __builtin_amdgcn_mfma_f32_32x32x16_f16(ah, bl, acc[ns], 0, 0, 0);
                acc[ns] = __builtin_amdgcn_mfma_f32_32x32x16_f16(al, bh, acc[ns], 0, 0, 0);
            }
        }
    }

    if (IS_QKV) {
        const int type = msub >> 8;            // 0=Q 1=K 2=V
        const int head = (msub >> 5) & 7;
        const int bh = b * 8 + head;
        if (type < 2) {
            u16* dst = type ? kT : qT;
#pragma unroll
            for (int ns = 0; ns < 4; ++ns) {
                const int n = n0 + ns * 32 + l31;
                u16* p = dst + ((size_t)bh * 1024 + n) * 32;
#pragma unroll
                for (int rp = 0; rp < 8; ++rp) {
                    const int r = rp * 2;
                    const int d = (r & 3) + 8 * (r >> 2) + 4 * h;   // even
                    *(unsigned*)&p[d] = packh2(acc[ns][r], acc[ns][r + 1]);
                }
            }
        } else {
#pragma unroll
            for (int ns = 0; ns < 4; ++ns) {
                const int n = n0 + ns * 32 + l31;
#pragma unroll
                for (int r = 0; r < 16; ++r) {
                    const int d = (r & 3) + 8 * (r >> 2) + 4 * h;
                    vN[((size_t)bh * 32 + d) * 1024 + n] = f2h(acc[ns][r]);
                }
            }
        }
    } else {
#pragma unroll
        for (int ns = 0; ns < 4; ++ns) {
            const int n = n0 + ns * 32 + l31;
#pragma unroll
            for (int r = 0; r < 16; ++r) {
                const int m = msub + (r & 3) + 8 * (r >> 2) + 4 * h;
                const size_t idx = ((size_t)b * 256 + m) * 1024 + n;
                Y[idx] = acc[ns][r] + res[idx];
            }
        }
    }
}

// ---------------- MFMA flash attention (unchanged from round 4) ----------------
__global__ __launch_bounds__(256) void attn_mfma_kernel(
    const u16* __restrict__ qT, const u16* __restrict__ kT,
    const u16* __restrict__ vN, float* __restrict__ ao)
{
    __shared__ __align__(16) u16 Ks[64 * 40];
    __shared__ __align__(16) u16 Vs[32 * 72];
    const int bh = blockIdx.y;
    const int b = bh >> 3, head = bh & 7;
    const int t = threadIdx.x;
    const int lane = t & 63;
    const int w = t >> 6;
    const int l31 = lane & 31;
    const int h = lane >> 5;
    const int ibase = blockIdx.x * 128 + w * 32;

    const u16* qrow = qT + ((size_t)bh * 1024 + ibase + l31) * 32;
    const f16x8 qf0 = *(const f16x8*)(qrow + h * 8);
    const f16x8 qf1 = *(const f16x8*)(qrow + 16 + h * 8);

    f32x16 out = {};
    float m = -1e30f, lsum = 0.f;

    const int kj = t >> 2, kq = t & 3;
    const u16* kg = kT + ((size_t)bh * 1024 + kj) * 32 + kq * 8;
    const int vd = t >> 3, vq = t & 7;
    const u16* vg = vN + ((size_t)bh * 32 + vd) * 1024 + vq * 8;

    for (int T = 0; T < 16; ++T) {
        __syncthreads();
        *(float4*)&Ks[kj * 40 + kq * 8] = *(const float4*)(kg + (size_t)T * 2048);
        *(float4*)&Vs[vd * 72 + vq * 8] = *(const float4*)(vg + T * 64);
        __syncthreads();

        const f16x8 kf00 = *(const f16x8*)&Ks[l31 * 40 + h * 8];
        const f16x8 kf01 = *(const f16x8*)&Ks[l31 * 40 + 16 + h * 8];
        const f16x8 kf10 = *(const f16x8*)&Ks[(32 + l31) * 40 + h * 8];
        const f16x8 kf11 = *(const f16x8*)&Ks[(32 + l31) * 40 + 16 + h * 8];
        f32x16 sA = {}, sB = {};
        sA = __builtin_amdgcn_mfma_f32_32x32x16_f16(kf00, qf0, sA, 0, 0, 0);
        sA = __builtin_amdgcn_mfma_f32_32x32x16_f16(kf01, qf1, sA, 0, 0, 0);
        sB = __builtin_amdgcn_mfma_f32_32x32x16_f16(kf10, qf0, sB, 0, 0, 0);
        sB = __builtin_amdgcn_mfma_f32_32x32x16_f16(kf11, qf1, sB, 0, 0, 0);

        float mt = fmaxf(vmax16(sA), vmax16(sB));
        mt = fmaxf(mt, __shfl_xor(mt, 32));
        if (!__all(mt <= m + 8.f)) {
            const float mn = fmaxf(m, mt);
            const float cor = __expf(m - mn);
            m = mn;
            lsum *= cor;
#pragma unroll
            for (int r = 0; r < 16; ++r) {
                const int src = (r & 3) + 8 * (r >> 2) + 4 * h;
                out[r] *= __shfl(cor, src);
            }
        }
#pragma unroll
        for (int r = 0; r < 16; ++r) {
            sA[r] = __expf(sA[r] - m);
            sB[r] = __expf(sB[r] - m);
        }
        float ps = vsum16(sA) + vsum16(sB);
        ps += __shfl_xor(ps, 32);
        lsum += ps;

        const f16x8 pf0 = packP<0>(sA, h);
        const f16x8 pf1 = packP<8>(sA, h);
        const f16x8 pf2 = packP<0>(sB, h);
        const f16x8 pf3 = packP<8>(sB, h);
        const f16x8 vf0 = *(const f16x8*)&Vs[l31 * 72 + h * 8];
        const f16x8 vf1 = *(const f16x8*)&Vs[l31 * 72 + 16 + h * 8];
        const f16x8 vf2 = *(const f16x8*)&Vs[l31 * 72 + 32 + h * 8];
        const f16x8 vf3 = *(const f16x8*)&Vs[l31 * 72 + 48 + h * 8];
        out = __builtin_amdgcn_mfma_f32_32x32x16_f16(pf0, vf0, out, 0, 0, 0);
        out = __builtin_amdgcn_mfma_f32_32x32x16_f16(pf1, vf1, out, 0, 0, 0);
        out = __builtin_amdgcn_mfma_f32_32x32x16_f16(pf2, vf2, out, 0, 0, 0);
        out = __builtin_amdgcn_mfma_f32_32x32x16_f16(pf3, vf3, out, 0, 0, 0);
    }

    const float linv = 1.f / lsum;
    const int cOut = b * 256 + head * 32 + blockIdx.x * 4 + w;
    float* og = ao + (size_t)cOut * 1024 + l31;
#pragma unroll
    for (int r = 0; r < 16; ++r) {
        const int crow = (r & 3) + 8 * (r >> 2) + 4 * h;
        const float sc = __shfl(linv, crow);
        og[crow * 32] = out[r] * sc;
    }
}

extern "C" void kernel_launch(void* const* d_in, const int* in_sizes, int n_in,
                              void* d_out, int out_size, void* d_ws, size_t ws_size,
                              hipStream_t stream) {
    const float* x      = (const float*)d_in[0];
    const float* norm_w = (const float*)d_in[1];
    const float* norm_b = (const float*)d_in[2];
    const float* qkv_w  = (const float*)d_in[3];
    const float* qkv_b  = (const float*)d_in[4];
    const float* out_w  = (const float*)d_in[5];
    const float* out_b  = (const float*)d_in[6];
    float* out = (float*)d_out;

    char* p = (char*)d_ws;
    float2* stats = (float2*)p;  p += 4096;
    u16* XTh = (u16*)p;  p += 4u * 1024 * 1024;
    u16* XTl = (u16*)p;  p += 4u * 1024 * 1024;
    u16* Wqh = (u16*)p;  p += 393216;
    u16* Wql = (u16*)p;  p += 393216;
    u16* Woh = (u16*)p;  p += 131072;
    u16* Wol = (u16*)p;  p += 131072;
    u16* qT  = (u16*)p;  p += 4u * 1024 * 1024;
    u16* kT  = (u16*)p;  p += 4u * 1024 * 1024;
    u16* vN  = (u16*)p;  p += 4u * 1024 * 1024;
    float* ao = (float*)p;  p += 8u * 1024 * 1024;
    u16* aoTh = (u16*)p; p += 4u * 1024 * 1024;
    u16* aoTl = (u16*)p; p += 4u * 1024 * 1024;

    gn_stats_kernel<<<dim3(32, NB), 256, 0, stream>>>(x, stats);
    wsplit_kernel<<<dim3(256), 256, 0, stream>>>(qkv_w, out_w, Wqh, Wql, Woh, Wol);
    tsplit_kernel<true><<<dim3(16, 4, NB), 256, 0, stream>>>(x, stats, norm_w, norm_b, XTh, XTl);
    mfma_gemm_kernel<true><<<dim3(8, 6, NB), 256, 0, stream>>>(
        Wqh, Wql, XTh, XTl, qkv_b, qT, kT, vN, nullptr, nullptr);
    attn_mfma_kernel<<<dim3(8, 64), 256, 0, stream>>>(qT, kT, vN, ao);
    tsplit_kernel<false><<<dim3(16, 4, NB), 256, 0, stream>>>(ao, nullptr, nullptr, nullptr, aoTh, aoTl);
    mfma_gemm_kernel<false><<<dim3(8, 2, NB), 256, 0, stream>>>(
        Woh, Wol, aoTh, aoTl, out_b, nullptr, nullptr, nullptr, x, out);
}

// Round 6
// 77.809 us; speedup vs baseline: 3.3687x; 1.1092x over previous
//
#include <hip/hip_runtime.h>
#include <hip/hip_bf16.h>

#define NB 8
#define NC 256
#define NHW 1024

typedef unsigned short u16;
typedef unsigned int u32;
using f16x8  = __attribute__((ext_vector_type(8))) _Float16;
using f32x16 = __attribute__((ext_vector_type(16))) float;
using u32x4  = __attribute__((ext_vector_type(4))) unsigned int;
using u16x8  = __attribute__((ext_vector_type(8))) unsigned short;

static __device__ inline u16 f2h(float f) {
    _Float16 h = (_Float16)f;
    return __builtin_bit_cast(u16, h);
}
static __device__ inline float h2f(u16 u) {
    return (float)__builtin_bit_cast(_Float16, u);
}
static __device__ inline unsigned pk2(float a, float b) {
    auto r = __builtin_amdgcn_cvt_pkrtz(a, b);
    return __builtin_bit_cast(unsigned, r);
}
static __device__ inline void gload16(const void* g, void* l) {
    __builtin_amdgcn_global_load_lds(
        (const __attribute__((address_space(1))) void*)g,
        (__attribute__((address_space(3))) void*)l, 16, 0, 0);
}
static __device__ inline float vmax16(const f32x16& v) {
    float m0 = fmaxf(fmaxf(v[0], v[1]), fmaxf(v[2], v[3]));
    float m1 = fmaxf(fmaxf(v[4], v[5]), fmaxf(v[6], v[7]));
    float m2 = fmaxf(fmaxf(v[8], v[9]), fmaxf(v[10], v[11]));
    float m3 = fmaxf(fmaxf(v[12], v[13]), fmaxf(v[14], v[15]));
    return fmaxf(fmaxf(m0, m1), fmaxf(m2, m3));
}
static __device__ inline float vsum16(const f32x16& v) {
    float s0 = (v[0] + v[1]) + (v[2] + v[3]);
    float s1 = (v[4] + v[5]) + (v[6] + v[7]);
    float s2 = (v[8] + v[9]) + (v[10] + v[11]);
    float s3 = (v[12] + v[13]) + (v[14] + v[15]);
    return (s0 + s1) + (s2 + s3);
}
template<int B>
static __device__ inline f16x8 packP(const f32x16& p, const int h) {
    unsigned u0 = pk2(p[B + 0], p[B + 1]);
    unsigned u1 = pk2(p[B + 2], p[B + 3]);
    unsigned u2 = pk2(p[B + 4], p[B + 5]);
    unsigned u3 = pk2(p[B + 6], p[B + 7]);
    unsigned pu0 = __shfl_xor(u0, 32);
    unsigned pu1 = __shfl_xor(u1, 32);
    unsigned pu2 = __shfl_xor(u2, 32);
    unsigned pu3 = __shfl_xor(u3, 32);
    u32x4 w;
    w[0] = h ? pu2 : u0;
    w[1] = h ? pu3 : u1;
    w[2] = h ? u2 : pu0;
    w[3] = h ? u3 : pu1;
    return __builtin_bit_cast(f16x8, w);
}

// ---------------- prep: GroupNorm stats (blocks 0..255) + weight split (256..511) ----------------
__global__ __launch_bounds__(256) void prep_kernel(
    const float* __restrict__ x, const float* __restrict__ qkv_w,
    const float* __restrict__ out_w, float2* __restrict__ stats,
    u16* __restrict__ Wqh, u16* __restrict__ Wql,
    u16* __restrict__ Woh, u16* __restrict__ Wol)
{
    __shared__ float rs[4][2];
    const int bid = blockIdx.x, t = threadIdx.x;
    if (bid < 256) {
        const int g = bid & 31, b = bid >> 5;
        const size_t base = ((size_t)b * NC + g * 8) * NHW;
        const float4* xi = (const float4*)(x + base);
        float sum = 0.f, sq = 0.f;
#pragma unroll
        for (int i = 0; i < 8; ++i) {
            float4 v = xi[t + i * 256];
            sum += v.x + v.y + v.z + v.w;
            sq += v.x * v.x + v.y * v.y + v.z * v.z + v.w * v.w;
        }
        const int lane = t & 63, wv = t >> 6;
#pragma unroll
        for (int o = 32; o > 0; o >>= 1) {
            sum += __shfl_down(sum, o, 64);
            sq += __shfl_down(sq, o, 64);
        }
        if (lane == 0) { rs[wv][0] = sum; rs[wv][1] = sq; }
        __syncthreads();
        if (t == 0) {
            float S = rs[0][0] + rs[1][0] + rs[2][0] + rs[3][0];
            float Q = rs[0][1] + rs[1][1] + rs[2][1] + rs[3][1];
            float mu = S * (1.f / 8192.f);
            float var = Q * (1.f / 8192.f) - mu * mu;
            stats[b * 32 + g] = make_float2(mu, rsqrtf(var + 1e-5f));
        }
    } else {
        const int f4 = (bid - 256) * 256 + t;   // 0..65535
        float4 v;
        u16 *dhp, *dlp;
        int e;
        if (f4 < 49152) {
            e = f4 * 4;
            v = *(const float4*)&qkv_w[e];
            if ((e >> 8) < 256) {
                const float s = 0.17677669529663687f;
                v.x *= s; v.y *= s; v.z *= s; v.w *= s;
            }
            dhp = Wqh; dlp = Wql;
        } else {
            e = (f4 - 49152) * 4;
            v = *(const float4*)&out_w[e];
            dhp = Woh; dlp = Wol;
        }
        ushort4 hh, ll;
        hh.x = f2h(v.x); ll.x = f2h(v.x - h2f(hh.x));
        hh.y = f2h(v.y); ll.y = f2h(v.y - h2f(hh.y));
        hh.z = f2h(v.z); ll.z = f2h(v.z - h2f(hh.z));
        hh.w = f2h(v.w); ll.w = f2h(v.w - h2f(hh.w));
        *(ushort4*)&dhp[e] = hh;
        *(ushort4*)&dlp[e] = ll;
    }
}

// ---------------- GroupNorm-fused transpose + split: x -> XT hi/lo [b][n=1024][k=256] f16 ----------------
__global__ __launch_bounds__(256) void tsplit_kernel(
    const float* __restrict__ src, const float2* __restrict__ stats,
    const float* __restrict__ gw, const float* __restrict__ gb,
    u16* __restrict__ dh, u16* __restrict__ dl)
{
    __shared__ float lds[64][68];
    const int b = blockIdx.z;
    const int c0 = blockIdx.y * 64, hw0 = blockIdx.x * 64;
    const int t = threadIdx.x;
    const int cL = t >> 4, hwL = (t & 15) * 4;
#pragma unroll
    for (int i = 0; i < 4; ++i) {
        const int c = c0 + cL + i * 16;
        float4 v = *(const float4*)&src[((size_t)b * 256 + c) * 1024 + hw0 + hwL];
        const float2 st = stats[b * 32 + (c >> 3)];
        const float sc = gw[c] * st.y;
        const float off = gb[c] - st.x * sc;
        v.x = v.x * sc + off; v.y = v.y * sc + off;
        v.z = v.z * sc + off; v.w = v.w * sc + off;
        *(float4*)&lds[cL + i * 16][hwL] = v;
    }
    __syncthreads();
    const int lane = t & 63, w = t >> 6;
    const int hwR = lane, cq = w * 16;
    u16x8 H0, H1, L0, L1;
#pragma unroll
    for (int j = 0; j < 8; ++j) {
        float f = lds[cq + j][hwR];
        u16 hh = f2h(f);
        H0[j] = hh;
        L0[j] = f2h(f - h2f(hh));
        float f2 = lds[cq + 8 + j][hwR];
        u16 hh2 = f2h(f2);
        H1[j] = hh2;
        L1[j] = f2h(f2 - h2f(hh2));
    }
    const size_t o = ((size_t)b * 1024 + hw0 + hwR) * 256 + c0 + cq;
    *(u16x8*)&dh[o] = H0; *(u16x8*)&dh[o + 8] = H1;
    *(u16x8*)&dl[o] = L0; *(u16x8*)&dl[o + 8] = L1;
}

// ---------------- QKV split-precision MFMA GEMM, gload_lds + dbuf 2-phase ----------------
// LDS [128 n][32 k] u16 linear, granule-swizzled: granule g of row n stored at g^(n&3).
__global__ __launch_bounds__(256) void qkv_gemm_kernel(
    const u16* __restrict__ Wh, const u16* __restrict__ Wl,
    const u16* __restrict__ Bh, const u16* __restrict__ Bl,
    const float* __restrict__ bias,
    u16* __restrict__ qT, u16* __restrict__ kT, u16* __restrict__ vN)
{
    __shared__ __align__(16) u16 sBh[2][4096];
    __shared__ __align__(16) u16 sBl[2][4096];
    const int b = blockIdx.z;
    const int m0 = blockIdx.y * 128, n0 = blockIdx.x * 128;
    const int t = threadIdx.x, w = t >> 6, lane = t & 63;
    const int l31 = lane & 31, h = lane >> 5;
    const int msub = m0 + w * 32;

    const u16* Bhb = Bh + ((size_t)b * 1024 + n0) * 256;
    const u16* Blb = Bl + ((size_t)b * 1024 + n0) * 256;
    const u16* War = Wh + (size_t)(msub + l31) * 256 + h * 8;
    const u16* Wbr = Wl + (size_t)(msub + l31) * 256 + h * 8;

    const float bscale = (msub < 256) ? 0.17677669529663687f : 1.0f;
    f32x16 acc[4];
#pragma unroll
    for (int r = 0; r < 16; ++r) {
        const int crow = (r & 3) + 8 * (r >> 2) + 4 * h;
        const float bv = bias[msub + crow] * bscale;
        acc[0][r] = bv; acc[1][r] = bv; acc[2][r] = bv; acc[3][r] = bv;
    }

    // staging: wave w stages rows [w*32, w*32+32), lane l -> row w*32 + j*16 + (l>>2), granule (l&3)^(row&3)
    const int srow = w * 32 + ((t & 63) >> 2);
    const int sg = (t & 3) ^ ((t >> 2) & 3);
    const u16* sh0 = Bhb + (size_t)srow * 256 + sg * 8;
    const u16* sl0 = Blb + (size_t)srow * 256 + sg * 8;
    const int wseg = w * 1024;

    int cur = 0;
    {
        gload16(sh0, &sBh[0][wseg]);
        gload16(sh0 + 16 * 256, &sBh[0][wseg + 512]);
        gload16(sl0, &sBl[0][wseg]);
        gload16(sl0 + 16 * 256, &sBl[0][wseg + 512]);
    }
    __syncthreads();
    for (int kc = 0; kc < 8; ++kc) {
        if (kc < 7) {
            const int o = (kc + 1) * 32;
            gload16(sh0 + o, &sBh[cur ^ 1][wseg]);
            gload16(sh0 + o + 16 * 256, &sBh[cur ^ 1][wseg + 512]);
            gload16(sl0 + o, &sBl[cur ^ 1][wseg]);
            gload16(sl0 + o + 16 * 256, &sBl[cur ^ 1][wseg + 512]);
        }
#pragma unroll
        for (int k16 = 0; k16 < 2; ++k16) {
            const f16x8 ah = *(const f16x8*)(War + kc * 32 + k16 * 16);
            const f16x8 al = *(const f16x8*)(Wbr + kc * 32 + k16 * 16);
            const int gi = ((k16 * 2 + h) ^ (l31 & 3)) * 8;
#pragma unroll
            for (int ns = 0; ns < 4; ++ns) {
                const int row = ns * 32 + l31;
                const f16x8 bh = *(const f16x8*)&sBh[cur][row * 32 + gi];
                const f16x8 bl = *(const f16x8*)&sBl[cur][row * 32 + gi];
                acc[ns] = __builtin_amdgcn_mfma_f32_32x32x16_f16(ah, bh, acc[ns], 0, 0, 0);
                acc[ns] = __builtin_amdgcn_mfma_f32_32x32x16_f16(ah, bl, acc[ns], 0, 0, 0);
                acc[ns] = __builtin_amdgcn_mfma_f32_32x32x16_f16(al, bh, acc[ns], 0, 0, 0);
            }
        }
        __syncthreads();
        cur ^= 1;
    }

    const int type = msub >> 8;            // 0=Q 1=K 2=V
    const int head = (msub >> 5) & 7;
    const int bh_ = b * 8 + head;
    if (type < 2) {
        u16* dst = type ? kT : qT;
#pragma unroll
        for (int ns = 0; ns < 4; ++ns) {
            const int n = n0 + ns * 32 + l31;
            u16* p = dst + ((size_t)bh_ * 1024 + n) * 32;
#pragma unroll
            for (int rp = 0; rp < 8; ++rp) {
                const int r = rp * 2;
                const int d = (r & 3) + 8 * (r >> 2) + 4 * h;   // even
                *(unsigned*)&p[d] = pk2(0.f, 0.f) * 0 + ((unsigned)f2h(acc[ns][r]) | ((unsigned)f2h(acc[ns][r + 1]) << 16));
            }
        }
    } else {
#pragma unroll
        for (int ns = 0; ns < 4; ++ns) {
            const int n = n0 + ns * 32 + l31;
#pragma unroll
            for (int r = 0; r < 16; ++r) {
                const int d = (r & 3) + 8 * (r >> 2) + 4 * h;
                vN[((size_t)bh_ * 32 + d) * 1024 + n] = f2h(acc[ns][r]);
            }
        }
    }
}

// ---------------- MFMA flash attention: gload_lds + dbuf 2-phase, packed hi/lo output ----------------
__global__ __launch_bounds__(256) void attn_mfma_kernel(
    const u16* __restrict__ qT, const u16* __restrict__ kT,
    const u16* __restrict__ vN, u32* __restrict__ aohl)
{
    __shared__ __align__(16) u16 Ks[2][2048];   // [64 j][32 d] granule-swz g^(j&3)
    __shared__ __align__(16) u16 Vs[2][2048];   // [32 d][64 j] granule-swz g^(d&7)
    const int bh = blockIdx.y;
    const int b = bh >> 3, head = bh & 7;
    const int t = threadIdx.x;
    const int lane = t & 63;
    const int w = t >> 6;
    const int l31 = lane & 31;
    const int h = lane >> 5;
    const int ibase = blockIdx.x * 128 + w * 32;

    const u16* qrow = qT + ((size_t)bh * 1024 + ibase + l31) * 32;
    const f16x8 qf0 = *(const f16x8*)(qrow + h * 8);
    const f16x8 qf1 = *(const f16x8*)(qrow + 16 + h * 8);

    f32x16 out = {};
    float m = -1e30f, lsum = 0.f;

    const u16* ksrc = kT + ((size_t)bh * 1024 + (t >> 2)) * 32 + ((t & 3) ^ ((t >> 2) & 3)) * 8;
    const u16* vsrc = vN + ((size_t)bh * 32 + (t >> 3)) * 1024 + ((t & 7) ^ ((t >> 3) & 7)) * 8;
    const int wseg = w * 512;

    gload16(ksrc, &Ks[0][wseg]);
    gload16(vsrc, &Vs[0][wseg]);
    __syncthreads();
    int cur = 0;
    for (int T = 0; T < 16; ++T) {
        if (T < 15) {
            gload16(ksrc + (size_t)(T + 1) * 2048, &Ks[cur ^ 1][wseg]);
            gload16(vsrc + (T + 1) * 64, &Vs[cur ^ 1][wseg]);
        }
        const int gk0 = (h ^ (l31 & 3)) * 8;
        const int gk1 = ((2 + h) ^ (l31 & 3)) * 8;
        const f16x8 kf00 = *(const f16x8*)&Ks[cur][l31 * 32 + gk0];
        const f16x8 kf01 = *(const f16x8*)&Ks[cur][l31 * 32 + gk1];
        const f16x8 kf10 = *(const f16x8*)&Ks[cur][(32 + l31) * 32 + gk0];
        const f16x8 kf11 = *(const f16x8*)&Ks[cur][(32 + l31) * 32 + gk1];
        f32x16 sA = {}, sB = {};
        sA = __builtin_amdgcn_mfma_f32_32x32x16_f16(kf00, qf0, sA, 0, 0, 0);
        sA = __builtin_amdgcn_mfma_f32_32x32x16_f16(kf01, qf1, sA, 0, 0, 0);
        sB = __builtin_amdgcn_mfma_f32_32x32x16_f16(kf10, qf0, sB, 0, 0, 0);
        sB = __builtin_amdgcn_mfma_f32_32x32x16_f16(kf11, qf1, sB, 0, 0, 0);

        float mt = fmaxf(vmax16(sA), vmax16(sB));
        mt = fmaxf(mt, __shfl_xor(mt, 32));
        if (!__all(mt <= m + 8.f)) {
            const float mn = fmaxf(m, mt);
            const float cor = __expf(m - mn);
            m = mn;
            lsum *= cor;
#pragma unroll
            for (int r = 0; r < 16; ++r) {
                const int src = (r & 3) + 8 * (r >> 2) + 4 * h;
                out[r] *= __shfl(cor, src);
            }
        }
#pragma unroll
        for (int r = 0; r < 16; ++r) {
            sA[r] = __expf(sA[r] - m);
            sB[r] = __expf(sB[r] - m);
        }
        float ps = vsum16(sA) + vsum16(sB);
        ps += __shfl_xor(ps, 32);
        lsum += ps;

        const f16x8 pf0 = packP<0>(sA, h);
        const f16x8 pf1 = packP<8>(sA, h);
        const f16x8 pf2 = packP<0>(sB, h);
        const f16x8 pf3 = packP<8>(sB, h);
        const int vx = l31 & 7;
        const f16x8 vf0 = *(const f16x8*)&Vs[cur][l31 * 64 + ((h    ) ^ vx) * 8];
        const f16x8 vf1 = *(const f16x8*)&Vs[cur][l31 * 64 + ((2 + h) ^ vx) * 8];
        const f16x8 vf2 = *(const f16x8*)&Vs[cur][l31 * 64 + ((4 + h) ^ vx) * 8];
        const f16x8 vf3 = *(const f16x8*)&Vs[cur][l31 * 64 + ((6 + h) ^ vx) * 8];
        out = __builtin_amdgcn_mfma_f32_32x32x16_f16(pf0, vf0, out, 0, 0, 0);
        out = __builtin_amdgcn_mfma_f32_32x32x16_f16(pf1, vf1, out, 0, 0, 0);
        out = __builtin_amdgcn_mfma_f32_32x32x16_f16(pf2, vf2, out, 0, 0, 0);
        out = __builtin_amdgcn_mfma_f32_32x32x16_f16(pf3, vf3, out, 0, 0, 0);
        __syncthreads();
        cur ^= 1;
    }

    const float linv = 1.f / lsum;
    const int cOut = b * 256 + head * 32 + blockIdx.x * 4 + w;
    u32* og = aohl + (size_t)cOut * 1024 + l31;
#pragma unroll
    for (int r = 0; r < 16; ++r) {
        const int crow = (r & 3) + 8 * (r >> 2) + 4 * h;
        const float sc = __shfl(linv, crow);
        const float val = out[r] * sc;
        const u16 hi = f2h(val);
        const u16 lo = f2h(val - h2f(hi));
        og[crow * 32] = (u32)hi | ((u32)lo << 16);
    }
}

// ---------------- OUT split-precision MFMA GEMM: B from packed aohl, split+transpose in staging ----------------
__global__ __launch_bounds__(256) void out_gemm_kernel(
    const u16* __restrict__ Wh, const u16* __restrict__ Wl,
    const u32* __restrict__ aohl, const float* __restrict__ bias,
    const float* __restrict__ res, float* __restrict__ Y)
{
    __shared__ __align__(16) u16 sBh[2][4096];
    __shared__ __align__(16) u16 sBl[2][4096];
    const int b = blockIdx.z;
    const int m0 = blockIdx.y * 64, n0 = blockIdx.x * 128;
    const int t = threadIdx.x, w = t >> 6, lane = t & 63;
    const int l31 = lane & 31, h = lane >> 5;
    const int wm = w >> 1, wn = w & 1;
    const int msub = m0 + wm * 32;

    const u16* War = Wh + (size_t)(msub + l31) * 256 + h * 8;
    const u16* Wbr = Wl + (size_t)(msub + l31) * 256 + h * 8;

    f32x16 acc[2];
#pragma unroll
    for (int r = 0; r < 16; ++r) {
        const int crow = (r & 3) + 8 * (r >> 2) + 4 * h;
        const float bv = bias[msub + crow];
        acc[0][r] = bv; acc[1][r] = bv;
    }

    const int kL = t >> 3, pb = (t & 7) * 16;
    const u32* asrc = aohl + ((size_t)b * 256 + kL) * 1024 + n0 + pb;
    u32x4 regs[4];

#define LOADC(kc) { _Pragma("unroll") for (int i = 0; i < 4; ++i) \
        regs[i] = *(const u32x4*)(asrc + (size_t)(kc) * 32 * 1024 + i * 4); }
#define WRITEC(buf) { _Pragma("unroll") for (int i = 0; i < 4; ++i) { \
        _Pragma("unroll") for (int e = 0; e < 4; ++e) { \
            const u32 v = regs[i][e]; \
            const int n = pb + i * 4 + e; \
            const int idx = n * 32 + ((kL >> 3) ^ (n & 3)) * 8 + (kL & 7); \
            sBh[buf][idx] = (u16)(v & 0xffff); \
            sBl[buf][idx] = (u16)(v >> 16); } } }

    LOADC(0); WRITEC(0);
    __syncthreads();
    int cur = 0;
    for (int kc = 0; kc < 8; ++kc) {
        if (kc < 7) LOADC(kc + 1);
#pragma unroll
        for (int k16 = 0; k16 < 2; ++k16) {
            const f16x8 ah = *(const f16x8*)(War + kc * 32 + k16 * 16);
            const f16x8 al = *(const f16x8*)(Wbr + kc * 32 + k16 * 16);
            const int gi = ((k16 * 2 + h) ^ (l31 & 3)) * 8;
#pragma unroll
            for (int ns = 0; ns < 2; ++ns) {
                const int row = wn * 64 + ns * 32 + l31;
                const f16x8 bh = *(const f16x8*)&sBh[cur][row * 32 + gi];
                const f16x8 bl = *(const f16x8*)&sBl[cur][row * 32 + gi];
                acc[ns] = __builtin_amdgcn_mfma_f32_32x32x16_f16(ah, bh, acc[ns], 0, 0, 0);
                acc[ns] = __builtin_amdgcn_mfma_f32_32x32x16_f16(ah, bl, acc[ns], 0, 0, 0);
                acc[ns] = __builtin_amdgcn_mfma_f32_32x32x16_f16(al, bh, acc[ns], 0, 0, 0);
            }
        }
        if (kc < 7) WRITEC(cur ^ 1);
        __syncthreads();
        cur ^= 1;
    }
#pragma unroll
    for (int ns = 0; ns < 2; ++ns) {
        const int n = n0 + wn * 64 + ns * 32 + l31;
#pragma unroll
        for (int r = 0; r < 16; ++r) {
            const int mm = msub + (r & 3) + 8 * (r >> 2) + 4 * h;
            const size_t idx = ((size_t)b * 256 + mm) * 1024 + n;
            Y[idx] = acc[ns][r] + res[idx];
        }
    }
#undef LOADC
#undef WRITEC
}

extern "C" void kernel_launch(void* const* d_in, const int* in_sizes, int n_in,
                              void* d_out, int out_size, void* d_ws, size_t ws_size,
                              hipStream_t stream) {
    const float* x      = (const float*)d_in[0];
    const float* norm_w = (const float*)d_in[1];
    const float* norm_b = (const float*)d_in[2];
    const float* qkv_w  = (const float*)d_in[3];
    const float* qkv_b  = (const float*)d_in[4];
    const float* out_w  = (const float*)d_in[5];
    const float* out_b  = (const float*)d_in[6];
    float* out = (float*)d_out;

    char* p = (char*)d_ws;
    float2* stats = (float2*)p;  p += 4096;
    u16* XTh = (u16*)p;  p += 4u * 1024 * 1024;
    u16* XTl = (u16*)p;  p += 4u * 1024 * 1024;
    u16* Wqh = (u16*)p;  p += 393216;
    u16* Wql = (u16*)p;  p += 393216;
    u16* Woh = (u16*)p;  p += 131072;
    u16* Wol = (u16*)p;  p += 131072;
    u16* qT  = (u16*)p;  p += 4u * 1024 * 1024;
    u16* kT  = (u16*)p;  p += 4u * 1024 * 1024;
    u16* vN  = (u16*)p;  p += 4u * 1024 * 1024;
    u32* aohl = (u32*)p; p += 4u * 1024 * 1024;

    prep_kernel<<<512, 256, 0, stream>>>(x, qkv_w, out_w, stats, Wqh, Wql, Woh, Wol);
    tsplit_kernel<<<dim3(16, 4, NB), 256, 0, stream>>>(x, stats, norm_w, norm_b, XTh, XTl);
    qkv_gemm_kernel<<<dim3(8, 6, NB), 256, 0, stream>>>(Wqh, Wql, XTh, XTl, qkv_b, qT, kT, vN);
    attn_mfma_kernel<<<dim3(8, 64), 256, 0, stream>>>(qT, kT, vN, aohl);
    out_gemm_kernel<<<dim3(8, 4, NB), 256, 0, stream>>>(Woh, Wol, aohl, out_b, x, out);
}

// Round 7
// 76.693 us; speedup vs baseline: 3.4177x; 1.0146x over previous
//
#include <hip/hip_runtime.h>
#include <hip/hip_bf16.h>

#define NB 8
#define NC 256
#define NHW 1024

typedef unsigned short u16;
typedef unsigned int u32;
using f16x8  = __attribute__((ext_vector_type(8))) _Float16;
using f32x16 = __attribute__((ext_vector_type(16))) float;
using u32x4  = __attribute__((ext_vector_type(4))) unsigned int;
using u16x8  = __attribute__((ext_vector_type(8))) unsigned short;

static __device__ inline u16 f2h(float f) {
    _Float16 h = (_Float16)f;
    return __builtin_bit_cast(u16, h);
}
static __device__ inline float h2f(u16 u) {
    return (float)__builtin_bit_cast(_Float16, u);
}
static __device__ inline unsigned pk2(float a, float b) {
    auto r = __builtin_amdgcn_cvt_pkrtz(a, b);
    return __builtin_bit_cast(unsigned, r);
}
static __device__ inline void gload16(const void* g, void* l) {
    __builtin_amdgcn_global_load_lds(
        (const __attribute__((address_space(1))) void*)g,
        (__attribute__((address_space(3))) void*)l, 16, 0, 0);
}
static __device__ inline float vmax16(const f32x16& v) {
    float m0 = fmaxf(fmaxf(v[0], v[1]), fmaxf(v[2], v[3]));
    float m1 = fmaxf(fmaxf(v[4], v[5]), fmaxf(v[6], v[7]));
    float m2 = fmaxf(fmaxf(v[8], v[9]), fmaxf(v[10], v[11]));
    float m3 = fmaxf(fmaxf(v[12], v[13]), fmaxf(v[14], v[15]));
    return fmaxf(fmaxf(m0, m1), fmaxf(m2, m3));
}
static __device__ inline float vsum16(const f32x16& v) {
    float s0 = (v[0] + v[1]) + (v[2] + v[3]);
    float s1 = (v[4] + v[5]) + (v[6] + v[7]);
    float s2 = (v[8] + v[9]) + (v[10] + v[11]);
    float s3 = (v[12] + v[13]) + (v[14] + v[15]);
    return (s0 + s1) + (s2 + s3);
}
template<int B>
static __device__ inline f16x8 packP(const f32x16& p, const int h) {
    unsigned u0 = pk2(p[B + 0], p[B + 1]);
    unsigned u1 = pk2(p[B + 2], p[B + 3]);
    unsigned u2 = pk2(p[B + 4], p[B + 5]);
    unsigned u3 = pk2(p[B + 6], p[B + 7]);
    unsigned pu0 = __shfl_xor(u0, 32);
    unsigned pu1 = __shfl_xor(u1, 32);
    unsigned pu2 = __shfl_xor(u2, 32);
    unsigned pu3 = __shfl_xor(u3, 32);
    u32x4 w;
    w[0] = h ? pu2 : u0;
    w[1] = h ? pu3 : u1;
    w[2] = h ? u2 : pu0;
    w[3] = h ? u3 : pu1;
    return __builtin_bit_cast(f16x8, w);
}

// ---------------- prep: GroupNorm stats (blocks 0..255) + weight split (256..511) ----------------
__global__ __launch_bounds__(256) void prep_kernel(
    const float* __restrict__ x, const float* __restrict__ qkv_w,
    const float* __restrict__ out_w, float2* __restrict__ stats,
    u16* __restrict__ Wqh, u16* __restrict__ Wql,
    u16* __restrict__ Woh, u16* __restrict__ Wol)
{
    __shared__ float rs[4][2];
    const int bid = blockIdx.x, t = threadIdx.x;
    if (bid < 256) {
        const int g = bid & 31, b = bid >> 5;
        const size_t base = ((size_t)b * NC + g * 8) * NHW;
        const float4* xi = (const float4*)(x + base);
        float sum = 0.f, sq = 0.f;
#pragma unroll
        for (int i = 0; i < 8; ++i) {
            float4 v = xi[t + i * 256];
            sum += v.x + v.y + v.z + v.w;
            sq += v.x * v.x + v.y * v.y + v.z * v.z + v.w * v.w;
        }
        const int lane = t & 63, wv = t >> 6;
#pragma unroll
        for (int o = 32; o > 0; o >>= 1) {
            sum += __shfl_down(sum, o, 64);
            sq += __shfl_down(sq, o, 64);
        }
        if (lane == 0) { rs[wv][0] = sum; rs[wv][1] = sq; }
        __syncthreads();
        if (t == 0) {
            float S = rs[0][0] + rs[1][0] + rs[2][0] + rs[3][0];
            float Q = rs[0][1] + rs[1][1] + rs[2][1] + rs[3][1];
            float mu = S * (1.f / 8192.f);
            float var = Q * (1.f / 8192.f) - mu * mu;
            stats[b * 32 + g] = make_float2(mu, rsqrtf(var + 1e-5f));
        }
    } else {
        const int f4 = (bid - 256) * 256 + t;   // 0..65535
        float4 v;
        u16 *dhp, *dlp;
        int e;
        if (f4 < 49152) {
            e = f4 * 4;
            v = *(const float4*)&qkv_w[e];
            if ((e >> 8) < 256) {
                const float s = 0.17677669529663687f;
                v.x *= s; v.y *= s; v.z *= s; v.w *= s;
            }
            dhp = Wqh; dlp = Wql;
        } else {
            e = (f4 - 49152) * 4;
            v = *(const float4*)&out_w[e];
            dhp = Woh; dlp = Wol;
        }
        ushort4 hh, ll;
        hh.x = f2h(v.x); ll.x = f2h(v.x - h2f(hh.x));
        hh.y = f2h(v.y); ll.y = f2h(v.y - h2f(hh.y));
        hh.z = f2h(v.z); ll.z = f2h(v.z - h2f(hh.z));
        hh.w = f2h(v.w); ll.w = f2h(v.w - h2f(hh.w));
        *(ushort4*)&dhp[e] = hh;
        *(ushort4*)&dlp[e] = ll;
    }
}

// ---------------- GroupNorm-fused transpose + split: x -> XT hi/lo [b][n=1024][k=256] f16 ----------------
__global__ __launch_bounds__(256) void tsplit_kernel(
    const float* __restrict__ src, const float2* __restrict__ stats,
    const float* __restrict__ gw, const float* __restrict__ gb,
    u16* __restrict__ dh, u16* __restrict__ dl)
{
    __shared__ float lds[64][68];
    const int b = blockIdx.z;
    const int c0 = blockIdx.y * 64, hw0 = blockIdx.x * 64;
    const int t = threadIdx.x;
    const int cL = t >> 4, hwL = (t & 15) * 4;
#pragma unroll
    for (int i = 0; i < 4; ++i) {
        const int c = c0 + cL + i * 16;
        float4 v = *(const float4*)&src[((size_t)b * 256 + c) * 1024 + hw0 + hwL];
        const float2 st = stats[b * 32 + (c >> 3)];
        const float sc = gw[c] * st.y;
        const float off = gb[c] - st.x * sc;
        v.x = v.x * sc + off; v.y = v.y * sc + off;
        v.z = v.z * sc + off; v.w = v.w * sc + off;
        *(float4*)&lds[cL + i * 16][hwL] = v;
    }
    __syncthreads();
    const int lane = t & 63, w = t >> 6;
    const int hwR = lane, cq = w * 16;
    u16x8 H0, H1, L0, L1;
#pragma unroll
    for (int j = 0; j < 8; ++j) {
        float f = lds[cq + j][hwR];
        u16 hh = f2h(f);
        H0[j] = hh;
        L0[j] = f2h(f - h2f(hh));
        float f2 = lds[cq + 8 + j][hwR];
        u16 hh2 = f2h(f2);
        H1[j] = hh2;
        L1[j] = f2h(f2 - h2f(hh2));
    }
    const size_t o = ((size_t)b * 1024 + hw0 + hwR) * 256 + c0 + cq;
    *(u16x8*)&dh[o] = H0; *(u16x8*)&dh[o + 8] = H1;
    *(u16x8*)&dl[o] = L0; *(u16x8*)&dl[o + 8] = L1;
}

// ---------------- QKV split-precision MFMA GEMM, 128m x 64n, gload_lds + dbuf ----------------
// LDS [64 n][32 k] u16 linear, granule-swizzled: granule g of row n at g^(n&3).
__global__ __launch_bounds__(256) void qkv_gemm_kernel(
    const u16* __restrict__ Wh, const u16* __restrict__ Wl,
    const u16* __restrict__ Bh, const u16* __restrict__ Bl,
    const float* __restrict__ bias,
    u16* __restrict__ qT, u16* __restrict__ kT, u16* __restrict__ vN)
{
    __shared__ __align__(16) u16 sBh[2][2048];
    __shared__ __align__(16) u16 sBl[2][2048];
    const int b = blockIdx.z;
    const int m0 = blockIdx.y * 128, n0 = blockIdx.x * 64;
    const int t = threadIdx.x, w = t >> 6, lane = t & 63;
    const int l31 = lane & 31, h = lane >> 5;
    const int msub = m0 + w * 32;

    const u16* Bhb = Bh + ((size_t)b * 1024 + n0) * 256;
    const u16* Blb = Bl + ((size_t)b * 1024 + n0) * 256;
    const u16* War = Wh + (size_t)(msub + l31) * 256 + h * 8;
    const u16* Wbr = Wl + (size_t)(msub + l31) * 256 + h * 8;

    const float bscale = (msub < 256) ? 0.17677669529663687f : 1.0f;
    f32x16 acc[2];
#pragma unroll
    for (int r = 0; r < 16; ++r) {
        const int crow = (r & 3) + 8 * (r >> 2) + 4 * h;
        const float bv = bias[msub + crow] * bscale;
        acc[0][r] = bv; acc[1][r] = bv;
    }

    // staging: wave w stages rows [w*16, w*16+16); lane -> row w*16 + (lane>>2), granule (lane&3)^(row&3)
    const int srow = (t >> 2) & 63;                 // == w*16 + (lane>>2)
    const int sg = (t & 3) ^ (srow & 3);
    const u16* sh0 = Bhb + (size_t)srow * 256 + sg * 8;
    const u16* sl0 = Blb + (size_t)srow * 256 + sg * 8;
    const int wseg = w * 512;

    gload16(sh0, &sBh[0][wseg]);
    gload16(sl0, &sBl[0][wseg]);
    __syncthreads();
    int cur = 0;
    for (int kc = 0; kc < 8; ++kc) {
        if (kc < 7) {
            const int o = (kc + 1) * 32;
            gload16(sh0 + o, &sBh[cur ^ 1][wseg]);
            gload16(sl0 + o, &sBl[cur ^ 1][wseg]);
        }
#pragma unroll
        for (int k16 = 0; k16 < 2; ++k16) {
            const f16x8 ah = *(const f16x8*)(War + kc * 32 + k16 * 16);
            const f16x8 al = *(const f16x8*)(Wbr + kc * 32 + k16 * 16);
            const int gi = ((k16 * 2 + h) ^ (l31 & 3)) * 8;
#pragma unroll
            for (int ns = 0; ns < 2; ++ns) {
                const int row = ns * 32 + l31;
                const f16x8 bh = *(const f16x8*)&sBh[cur][row * 32 + gi];
                const f16x8 bl = *(const f16x8*)&sBl[cur][row * 32 + gi];
                acc[ns] = __builtin_amdgcn_mfma_f32_32x32x16_f16(ah, bh, acc[ns], 0, 0, 0);
                acc[ns] = __builtin_amdgcn_mfma_f32_32x32x16_f16(ah, bl, acc[ns], 0, 0, 0);
                acc[ns] = __builtin_amdgcn_mfma_f32_32x32x16_f16(al, bh, acc[ns], 0, 0, 0);
            }
        }
        __syncthreads();
        cur ^= 1;
    }

    const int type = msub >> 8;            // 0=Q 1=K 2=V
    const int head = (msub >> 5) & 7;
    const int bh_ = b * 8 + head;
    if (type < 2) {
        u16* dst = type ? kT : qT;
#pragma unroll
        for (int ns = 0; ns < 2; ++ns) {
            const int n = n0 + ns * 32 + l31;
            u16* p = dst + ((size_t)bh_ * 1024 + n) * 32;
#pragma unroll
            for (int rp = 0; rp < 8; ++rp) {
                const int r = rp * 2;
                const int d = (r & 3) + 8 * (r >> 2) + 4 * h;   // even
                *(unsigned*)&p[d] = (unsigned)f2h(acc[ns][r]) | ((unsigned)f2h(acc[ns][r + 1]) << 16);
            }
        }
    } else {
#pragma unroll
        for (int ns = 0; ns < 2; ++ns) {
            const int n = n0 + ns * 32 + l31;
#pragma unroll
            for (int r = 0; r < 16; ++r) {
                const int d = (r & 3) + 8 * (r >> 2) + 4 * h;
                vN[((size_t)bh_ * 32 + d) * 1024 + n] = f2h(acc[ns][r]);
            }
        }
    }
}

// ---------------- MFMA flash attention: 1D grid (XCD = head%8), gload_lds dbuf ----------------
__global__ __launch_bounds__(256) void attn_mfma_kernel(
    const u16* __restrict__ qT, const u16* __restrict__ kT,
    const u16* __restrict__ vN, u32* __restrict__ aohl)
{
    __shared__ __align__(16) u16 Ks[2][2048];   // [64 j][32 d] granule-swz g^(j&3)
    __shared__ __align__(16) u16 Vs[2][2048];   // [32 d][64 j] granule-swz g^(d&7)
    const int bid = blockIdx.x;
    const int itile = bid >> 6, bh = bid & 63;   // XCD = bid%8 = head%8 -> K/V L2-resident
    const int b = bh >> 3, head = bh & 7;
    const int t = threadIdx.x;
    const int lane = t & 63;
    const int w = t >> 6;
    const int l31 = lane & 31;
    const int h = lane >> 5;
    const int ibase = itile * 128 + w * 32;

    const u16* qrow = qT + ((size_t)bh * 1024 + ibase + l31) * 32;
    const f16x8 qf0 = *(const f16x8*)(qrow + h * 8);
    const f16x8 qf1 = *(const f16x8*)(qrow + 16 + h * 8);

    f32x16 out = {};
    float m = -1e30f, lsum = 0.f;

    const u16* ksrc = kT + ((size_t)bh * 1024 + (t >> 2)) * 32 + ((t & 3) ^ ((t >> 2) & 3)) * 8;
    const u16* vsrc = vN + ((size_t)bh * 32 + (t >> 3)) * 1024 + ((t & 7) ^ ((t >> 3) & 7)) * 8;
    const int wseg = w * 512;

    gload16(ksrc, &Ks[0][wseg]);
    gload16(vsrc, &Vs[0][wseg]);
    __syncthreads();
    int cur = 0;
    for (int T = 0; T < 16; ++T) {
        if (T < 15) {
            gload16(ksrc + (size_t)(T + 1) * 2048, &Ks[cur ^ 1][wseg]);
            gload16(vsrc + (T + 1) * 64, &Vs[cur ^ 1][wseg]);
        }
        const int gk0 = (h ^ (l31 & 3)) * 8;
        const int gk1 = ((2 + h) ^ (l31 & 3)) * 8;
        const f16x8 kf00 = *(const f16x8*)&Ks[cur][l31 * 32 + gk0];
        const f16x8 kf01 = *(const f16x8*)&Ks[cur][l31 * 32 + gk1];
        const f16x8 kf10 = *(const f16x8*)&Ks[cur][(32 + l31) * 32 + gk0];
        const f16x8 kf11 = *(const f16x8*)&Ks[cur][(32 + l31) * 32 + gk1];
        f32x16 sA = {}, sB = {};
        sA = __builtin_amdgcn_mfma_f32_32x32x16_f16(kf00, qf0, sA, 0, 0, 0);
        sA = __builtin_amdgcn_mfma_f32_32x32x16_f16(kf01, qf1, sA, 0, 0, 0);
        sB = __builtin_amdgcn_mfma_f32_32x32x16_f16(kf10, qf0, sB, 0, 0, 0);
        sB = __builtin_amdgcn_mfma_f32_32x32x16_f16(kf11, qf1, sB, 0, 0, 0);

        float mt = fmaxf(vmax16(sA), vmax16(sB));
        mt = fmaxf(mt, __shfl_xor(mt, 32));
        if (!__all(mt <= m + 8.f)) {
            const float mn = fmaxf(m, mt);
            const float cor = __expf(m - mn);
            m = mn;
            lsum *= cor;
#pragma unroll
            for (int r = 0; r < 16; ++r) {
                const int src = (r & 3) + 8 * (r >> 2) + 4 * h;
                out[r] *= __shfl(cor, src);
            }
        }
#pragma unroll
        for (int r = 0; r < 16; ++r) {
            sA[r] = __expf(sA[r] - m);
            sB[r] = __expf(sB[r] - m);
        }
        float ps = vsum16(sA) + vsum16(sB);
        ps += __shfl_xor(ps, 32);
        lsum += ps;

        const f16x8 pf0 = packP<0>(sA, h);
        const f16x8 pf1 = packP<8>(sA, h);
        const f16x8 pf2 = packP<0>(sB, h);
        const f16x8 pf3 = packP<8>(sB, h);
        const int vx = l31 & 7;
        const f16x8 vf0 = *(const f16x8*)&Vs[cur][l31 * 64 + ((h    ) ^ vx) * 8];
        const f16x8 vf1 = *(const f16x8*)&Vs[cur][l31 * 64 + ((2 + h) ^ vx) * 8];
        const f16x8 vf2 = *(const f16x8*)&Vs[cur][l31 * 64 + ((4 + h) ^ vx) * 8];
        const f16x8 vf3 = *(const f16x8*)&Vs[cur][l31 * 64 + ((6 + h) ^ vx) * 8];
        out = __builtin_amdgcn_mfma_f32_32x32x16_f16(pf0, vf0, out, 0, 0, 0);
        out = __builtin_amdgcn_mfma_f32_32x32x16_f16(pf1, vf1, out, 0, 0, 0);
        out = __builtin_amdgcn_mfma_f32_32x32x16_f16(pf2, vf2, out, 0, 0, 0);
        out = __builtin_amdgcn_mfma_f32_32x32x16_f16(pf3, vf3, out, 0, 0, 0);
        __syncthreads();
        cur ^= 1;
    }

    const float linv = 1.f / lsum;
    const int cOut = b * 256 + head * 32 + itile * 4 + w;
    u32* og = aohl + (size_t)cOut * 1024 + l31;
#pragma unroll
    for (int r = 0; r < 16; ++r) {
        const int crow = (r & 3) + 8 * (r >> 2) + 4 * h;
        const float sc = __shfl(linv, crow);
        const float val = out[r] * sc;
        const u16 hi = f2h(val);
        const u16 lo = f2h(val - h2f(hi));
        og[crow * 32] = (u32)hi | ((u32)lo << 16);
    }
}

// ---------------- OUT split-precision MFMA GEMM: 64m x 64n, B from packed aohl ----------------
__global__ __launch_bounds__(256) void out_gemm_kernel(
    const u16* __restrict__ Wh, const u16* __restrict__ Wl,
    const u32* __restrict__ aohl, const float* __restrict__ bias,
    const float* __restrict__ res, float* __restrict__ Y)
{
    __shared__ __align__(16) u16 sBh[2][2048];
    __shared__ __align__(16) u16 sBl[2][2048];
    const int b = blockIdx.z;
    const int m0 = blockIdx.y * 64, n0 = blockIdx.x * 64;
    const int t = threadIdx.x, w = t >> 6, lane = t & 63;
    const int l31 = lane & 31, h = lane >> 5;
    const int wm = w >> 1, wn = w & 1;
    const int msub = m0 + wm * 32;

    const u16* War = Wh + (size_t)(msub + l31) * 256 + h * 8;
    const u16* Wbr = Wl + (size_t)(msub + l31) * 256 + h * 8;

    f32x16 acc;
#pragma unroll
    for (int r = 0; r < 16; ++r) {
        const int crow = (r & 3) + 8 * (r >> 2) + 4 * h;
        acc[r] = bias[msub + crow];
    }

    const int kL = t >> 3, pb = (t & 7) * 8;
    const u32* asrc = aohl + ((size_t)b * 256 + kL) * 1024 + n0 + pb;
    u32x4 regs[2];

#define LOADC(kc) { _Pragma("unroll") for (int i = 0; i < 2; ++i) \
        regs[i] = *(const u32x4*)(asrc + (size_t)(kc) * 32 * 1024 + i * 4); }
#define WRITEC(buf) { _Pragma("unroll") for (int i = 0; i < 2; ++i) { \
        _Pragma("unroll") for (int e = 0; e < 4; ++e) { \
            const u32 v = regs[i][e]; \
            const int n = pb + i * 4 + e; \
            const int idx = n * 32 + ((kL >> 3) ^ (n & 3)) * 8 + (kL & 7); \
            sBh[buf][idx] = (u16)(v & 0xffff); \
            sBl[buf][idx] = (u16)(v >> 16); } } }

    LOADC(0); WRITEC(0);
    __syncthreads();
    int cur = 0;
    for (int kc = 0; kc < 8; ++kc) {
        if (kc < 7) LOADC(kc + 1);
#pragma unroll
        for (int k16 = 0; k16 < 2; ++k16) {
            const f16x8 ah = *(const f16x8*)(War + kc * 32 + k16 * 16);
            const f16x8 al = *(const f16x8*)(Wbr + kc * 32 + k16 * 16);
            const int gi = ((k16 * 2 + h) ^ (l31 & 3)) * 8;
            const int row = wn * 32 + l31;
            const f16x8 bh = *(const f16x8*)&sBh[cur][row * 32 + gi];
            const f16x8 bl = *(const f16x8*)&sBl[cur][row * 32 + gi];
            acc = __builtin_amdgcn_mfma_f32_32x32x16_f16(ah, bh, acc, 0, 0, 0);
            acc = __builtin_amdgcn_mfma_f32_32x32x16_f16(ah, bl, acc, 0, 0, 0);
            acc = __builtin_amdgcn_mfma_f32_32x32x16_f16(al, bh, acc, 0, 0, 0);
        }
        if (kc < 7) WRITEC(cur ^ 1);
        __syncthreads();
        cur ^= 1;
    }
    const int n = n0 + wn * 32 + l31;
#pragma unroll
    for (int r = 0; r < 16; ++r) {
        const int mm = msub + (r & 3) + 8 * (r >> 2) + 4 * h;
        const size_t idx = ((size_t)b * 256 + mm) * 1024 + n;
        Y[idx] = acc[r] + res[idx];
    }
#undef LOADC
#undef WRITEC
}

extern "C" void kernel_launch(void* const* d_in, const int* in_sizes, int n_in,
                              void* d_out, int out_size, void* d_ws, size_t ws_size,
                              hipStream_t stream) {
    const float* x      = (const float*)d_in[0];
    const float* norm_w = (const float*)d_in[1];
    const float* norm_b = (const float*)d_in[2];
    const float* qkv_w  = (const float*)d_in[3];
    const float* qkv_b  = (const float*)d_in[4];
    const float* out_w  = (const float*)d_in[5];
    const float* out_b  = (const float*)d_in[6];
    float* out = (float*)d_out;

    char* p = (char*)d_ws;
    float2* stats = (float2*)p;  p += 4096;
    u16* XTh = (u16*)p;  p += 4u * 1024 * 1024;
    u16* XTl = (u16*)p;  p += 4u * 1024 * 1024;
    u16* Wqh = (u16*)p;  p += 393216;
    u16* Wql = (u16*)p;  p += 393216;
    u16* Woh = (u16*)p;  p += 131072;
    u16* Wol = (u16*)p;  p += 131072;
    u16* qT  = (u16*)p;  p += 4u * 1024 * 1024;
    u16* kT  = (u16*)p;  p += 4u * 1024 * 1024;
    u16* vN  = (u16*)p;  p += 4u * 1024 * 1024;
    u32* aohl = (u32*)p; p += 4u * 1024 * 1024;

    prep_kernel<<<512, 256, 0, stream>>>(x, qkv_w, out_w, stats, Wqh, Wql, Woh, Wol);
    tsplit_kernel<<<dim3(16, 4, NB), 256, 0, stream>>>(x, stats, norm_w, norm_b, XTh, XTl);
    qkv_gemm_kernel<<<dim3(16, 6, NB), 256, 0, stream>>>(Wqh, Wql, XTh, XTl, qkv_b, qT, kT, vN);
    attn_mfma_kernel<<<512, 256, 0, stream>>>(qT, kT, vN, aohl);
    out_gemm_kernel<<<dim3(16, 4, NB), 256, 0, stream>>>(Woh, Wol, aohl, out_b, x, out);
}

// Round 8
// 62.256 us; speedup vs baseline: 4.2103x; 1.2319x over previous
//
#include <hip/hip_runtime.h>
#include <hip/hip_bf16.h>

#define NB 8
#define NC 256
#define NHW 1024

typedef unsigned short u16;
typedef unsigned int u32;
using f16x8  = __attribute__((ext_vector_type(8))) _Float16;
using f32x16 = __attribute__((ext_vector_type(16))) float;
using u32x4  = __attribute__((ext_vector_type(4))) unsigned int;
using u16x8  = __attribute__((ext_vector_type(8))) unsigned short;

static __device__ inline u16 f2h(float f) {
    _Float16 h = (_Float16)f;
    return __builtin_bit_cast(u16, h);
}
static __device__ inline float h2f(u16 u) {
    return (float)__builtin_bit_cast(_Float16, u);
}
static __device__ inline unsigned pk2(float a, float b) {
    auto r = __builtin_amdgcn_cvt_pkrtz(a, b);
    return __builtin_bit_cast(unsigned, r);
}
static __device__ inline void gload16(const void* g, void* l) {
    __builtin_amdgcn_global_load_lds(
        (const __attribute__((address_space(1))) void*)g,
        (__attribute__((address_space(3))) void*)l, 16, 0, 0);
}
static __device__ inline float vmax16(const f32x16& v) {
    float m0 = fmaxf(fmaxf(v[0], v[1]), fmaxf(v[2], v[3]));
    float m1 = fmaxf(fmaxf(v[4], v[5]), fmaxf(v[6], v[7]));
    float m2 = fmaxf(fmaxf(v[8], v[9]), fmaxf(v[10], v[11]));
    float m3 = fmaxf(fmaxf(v[12], v[13]), fmaxf(v[14], v[15]));
    return fmaxf(fmaxf(m0, m1), fmaxf(m2, m3));
}
static __device__ inline float vsum16(const f32x16& v) {
    float s0 = (v[0] + v[1]) + (v[2] + v[3]);
    float s1 = (v[4] + v[5]) + (v[6] + v[7]);
    float s2 = (v[8] + v[9]) + (v[10] + v[11]);
    float s3 = (v[12] + v[13]) + (v[14] + v[15]);
    return (s0 + s1) + (s2 + s3);
}
template<int B>
static __device__ inline f16x8 packP(const f32x16& p, const int h) {
    unsigned u0 = pk2(p[B + 0], p[B + 1]);
    unsigned u1 = pk2(p[B + 2], p[B + 3]);
    unsigned u2 = pk2(p[B + 4], p[B + 5]);
    unsigned u3 = pk2(p[B + 6], p[B + 7]);
    unsigned pu0 = __shfl_xor(u0, 32);
    unsigned pu1 = __shfl_xor(u1, 32);
    unsigned pu2 = __shfl_xor(u2, 32);
    unsigned pu3 = __shfl_xor(u3, 32);
    u32x4 w;
    w[0] = h ? pu2 : u0;
    w[1] = h ? pu3 : u1;
    w[2] = h ? u2 : pu0;
    w[3] = h ? u3 : pu1;
    return __builtin_bit_cast(f16x8, w);
}

// ---------------- prep: GroupNorm stats (blocks 0..255) + weight f16 convert (256..511) ----------------
__global__ __launch_bounds__(256) void prep_kernel(
    const float* __restrict__ x, const float* __restrict__ qkv_w,
    const float* __restrict__ out_w, float2* __restrict__ stats,
    u16* __restrict__ Wq, u16* __restrict__ Wo)
{
    __shared__ float rs[4][2];
    const int bid = blockIdx.x, t = threadIdx.x;
    if (bid < 256) {
        const int g = bid & 31, b = bid >> 5;
        const size_t base = ((size_t)b * NC + g * 8) * NHW;
        const float4* xi = (const float4*)(x + base);
        float sum = 0.f, sq = 0.f;
#pragma unroll
        for (int i = 0; i < 8; ++i) {
            float4 v = xi[t + i * 256];
            sum += v.x + v.y + v.z + v.w;
            sq += v.x * v.x + v.y * v.y + v.z * v.z + v.w * v.w;
        }
        const int lane = t & 63, wv = t >> 6;
#pragma unroll
        for (int o = 32; o > 0; o >>= 1) {
            sum += __shfl_down(sum, o, 64);
            sq += __shfl_down(sq, o, 64);
        }
        if (lane == 0) { rs[wv][0] = sum; rs[wv][1] = sq; }
        __syncthreads();
        if (t == 0) {
            float S = rs[0][0] + rs[1][0] + rs[2][0] + rs[3][0];
            float Q = rs[0][1] + rs[1][1] + rs[2][1] + rs[3][1];
            float mu = S * (1.f / 8192.f);
            float var = Q * (1.f / 8192.f) - mu * mu;
            stats[b * 32 + g] = make_float2(mu, rsqrtf(var + 1e-5f));
        }
    } else {
        const int f4 = (bid - 256) * 256 + t;   // 0..65535
        float4 v;
        u16* dhp;
        int e;
        if (f4 < 49152) {
            e = f4 * 4;
            v = *(const float4*)&qkv_w[e];
            if ((e >> 8) < 256) {
                const float s = 0.17677669529663687f;
                v.x *= s; v.y *= s; v.z *= s; v.w *= s;
            }
            dhp = Wq;
        } else {
            e = (f4 - 49152) * 4;
            v = *(const float4*)&out_w[e];
            dhp = Wo;
        }
        ushort4 hh;
        hh.x = f2h(v.x); hh.y = f2h(v.y); hh.z = f2h(v.z); hh.w = f2h(v.w);
        *(ushort4*)&dhp[e] = hh;
    }
}

// ---------------- GroupNorm-fused transpose: x -> XT [b][n=1024][k=256] f16 ----------------
__global__ __launch_bounds__(256) void tsplit_kernel(
    const float* __restrict__ src, const float2* __restrict__ stats,
    const float* __restrict__ gw, const float* __restrict__ gb,
    u16* __restrict__ dh)
{
    __shared__ float lds[64][68];
    const int b = blockIdx.z;
    const int c0 = blockIdx.y * 64, hw0 = blockIdx.x * 64;
    const int t = threadIdx.x;
    const int cL = t >> 4, hwL = (t & 15) * 4;
#pragma unroll
    for (int i = 0; i < 4; ++i) {
        const int c = c0 + cL + i * 16;
        float4 v = *(const float4*)&src[((size_t)b * 256 + c) * 1024 + hw0 + hwL];
        const float2 st = stats[b * 32 + (c >> 3)];
        const float sc = gw[c] * st.y;
        const float off = gb[c] - st.x * sc;
        v.x = v.x * sc + off; v.y = v.y * sc + off;
        v.z = v.z * sc + off; v.w = v.w * sc + off;
        *(float4*)&lds[cL + i * 16][hwL] = v;
    }
    __syncthreads();
    const int lane = t & 63, w = t >> 6;
    const int hwR = lane, cq = w * 16;
    u16x8 H0, H1;
#pragma unroll
    for (int j = 0; j < 8; ++j) {
        H0[j] = f2h(lds[cq + j][hwR]);
        H1[j] = f2h(lds[cq + 8 + j][hwR]);
    }
    const size_t o = ((size_t)b * 1024 + hw0 + hwR) * 256 + c0 + cq;
    *(u16x8*)&dh[o] = H0; *(u16x8*)&dh[o + 8] = H1;
}

// ---------------- QKV f16 MFMA GEMM, 128m x 64n, gload_lds + dbuf ----------------
// LDS [64 n][32 k] u16 linear, granule-swizzled: granule g of row n at g^(n&3).
__global__ __launch_bounds__(256) void qkv_gemm_kernel(
    const u16* __restrict__ W, const u16* __restrict__ B,
    const float* __restrict__ bias,
    u16* __restrict__ qT, u16* __restrict__ kT, u16* __restrict__ vN)
{
    __shared__ __align__(16) u16 sB[2][2048];
    const int b = blockIdx.z;
    const int m0 = blockIdx.y * 128, n0 = blockIdx.x * 64;
    const int t = threadIdx.x, w = t >> 6, lane = t & 63;
    const int l31 = lane & 31, h = lane >> 5;
    const int msub = m0 + w * 32;

    const u16* Bb = B + ((size_t)b * 1024 + n0) * 256;
    const u16* War = W + (size_t)(msub + l31) * 256 + h * 8;

    const float bscale = (msub < 256) ? 0.17677669529663687f : 1.0f;
    f32x16 acc[2];
#pragma unroll
    for (int r = 0; r < 16; ++r) {
        const int crow = (r & 3) + 8 * (r >> 2) + 4 * h;
        const float bv = bias[msub + crow] * bscale;
        acc[0][r] = bv; acc[1][r] = bv;
    }

    // staging: lane -> row (t>>2)&63, granule (t&3)^(row&3)
    const int srow = (t >> 2) & 63;
    const int sg = (t & 3) ^ (srow & 3);
    const u16* sh0 = Bb + (size_t)srow * 256 + sg * 8;
    const int wseg = w * 512;

    gload16(sh0, &sB[0][wseg]);
    __syncthreads();
    int cur = 0;
    for (int kc = 0; kc < 8; ++kc) {
        if (kc < 7) {
            gload16(sh0 + (kc + 1) * 32, &sB[cur ^ 1][wseg]);
        }
#pragma unroll
        for (int k16 = 0; k16 < 2; ++k16) {
            const f16x8 ah = *(const f16x8*)(War + kc * 32 + k16 * 16);
            const int gi = ((k16 * 2 + h) ^ (l31 & 3)) * 8;
#pragma unroll
            for (int ns = 0; ns < 2; ++ns) {
                const int row = ns * 32 + l31;
                const f16x8 bh = *(const f16x8*)&sB[cur][row * 32 + gi];
                acc[ns] = __builtin_amdgcn_mfma_f32_32x32x16_f16(ah, bh, acc[ns], 0, 0, 0);
            }
        }
        __syncthreads();
        cur ^= 1;
    }

    const int type = msub >> 8;            // 0=Q 1=K 2=V
    const int head = (msub >> 5) & 7;
    const int bh_ = b * 8 + head;
    if (type < 2) {
        u16* dst = type ? kT : qT;
#pragma unroll
        for (int ns = 0; ns < 2; ++ns) {
            const int n = n0 + ns * 32 + l31;
            u16* p = dst + ((size_t)bh_ * 1024 + n) * 32;
#pragma unroll
            for (int rp = 0; rp < 8; ++rp) {
                const int r = rp * 2;
                const int d = (r & 3) + 8 * (r >> 2) + 4 * h;   // even
                *(unsigned*)&p[d] = (unsigned)f2h(acc[ns][r]) | ((unsigned)f2h(acc[ns][r + 1]) << 16);
            }
        }
    } else {
#pragma unroll
        for (int ns = 0; ns < 2; ++ns) {
            const int n = n0 + ns * 32 + l31;
#pragma unroll
            for (int r = 0; r < 16; ++r) {
                const int d = (r & 3) + 8 * (r >> 2) + 4 * h;
                vN[((size_t)bh_ * 32 + d) * 1024 + n] = f2h(acc[ns][r]);
            }
        }
    }
}

// ---------------- MFMA flash attention: 1D grid (XCD = head%8), gload_lds dbuf, f16 out ----------------
__global__ __launch_bounds__(256) void attn_mfma_kernel(
    const u16* __restrict__ qT, const u16* __restrict__ kT,
    const u16* __restrict__ vN, u16* __restrict__ ao)
{
    __shared__ __align__(16) u16 Ks[2][2048];   // [64 j][32 d] granule-swz g^(j&3)
    __shared__ __align__(16) u16 Vs[2][2048];   // [32 d][64 j] granule-swz g^(d&7)
    const int bid = blockIdx.x;
    const int itile = bid >> 6, bh = bid & 63;   // XCD = bid%8 = head%8 -> K/V L2-resident
    const int b = bh >> 3, head = bh & 7;
    const int t = threadIdx.x;
    const int lane = t & 63;
    const int w = t >> 6;
    const int l31 = lane & 31;
    const int h = lane >> 5;
    const int ibase = itile * 128 + w * 32;

    const u16* qrow = qT + ((size_t)bh * 1024 + ibase + l31) * 32;
    const f16x8 qf0 = *(const f16x8*)(qrow + h * 8);
    const f16x8 qf1 = *(const f16x8*)(qrow + 16 + h * 8);

    f32x16 out = {};
    float m = -1e30f, lsum = 0.f;

    const u16* ksrc = kT + ((size_t)bh * 1024 + (t >> 2)) * 32 + ((t & 3) ^ ((t >> 2) & 3)) * 8;
    const u16* vsrc = vN + ((size_t)bh * 32 + (t >> 3)) * 1024 + ((t & 7) ^ ((t >> 3) & 7)) * 8;
    const int wseg = w * 512;

    gload16(ksrc, &Ks[0][wseg]);
    gload16(vsrc, &Vs[0][wseg]);
    __syncthreads();
    int cur = 0;
    for (int T = 0; T < 16; ++T) {
        if (T < 15) {
            gload16(ksrc + (size_t)(T + 1) * 2048, &Ks[cur ^ 1][wseg]);
            gload16(vsrc + (T + 1) * 64, &Vs[cur ^ 1][wseg]);
        }
        const int gk0 = (h ^ (l31 & 3)) * 8;
        const int gk1 = ((2 + h) ^ (l31 & 3)) * 8;
        const f16x8 kf00 = *(const f16x8*)&Ks[cur][l31 * 32 + gk0];
        const f16x8 kf01 = *(const f16x8*)&Ks[cur][l31 * 32 + gk1];
        const f16x8 kf10 = *(const f16x8*)&Ks[cur][(32 + l31) * 32 + gk0];
        const f16x8 kf11 = *(const f16x8*)&Ks[cur][(32 + l31) * 32 + gk1];
        f32x16 sA = {}, sB = {};
        sA = __builtin_amdgcn_mfma_f32_32x32x16_f16(kf00, qf0, sA, 0, 0, 0);
        sA = __builtin_amdgcn_mfma_f32_32x32x16_f16(kf01, qf1, sA, 0, 0, 0);
        sB = __builtin_amdgcn_mfma_f32_32x32x16_f16(kf10, qf0, sB, 0, 0, 0);
        sB = __builtin_amdgcn_mfma_f32_32x32x16_f16(kf11, qf1, sB, 0, 0, 0);

        float mt = fmaxf(vmax16(sA), vmax16(sB));
        mt = fmaxf(mt, __shfl_xor(mt, 32));
        if (!__all(mt <= m + 8.f)) {
            const float mn = fmaxf(m, mt);
            const float cor = __expf(m - mn);
            m = mn;
            lsum *= cor;
#pragma unroll
            for (int r = 0; r < 16; ++r) {
                const int src = (r & 3) + 8 * (r >> 2) + 4 * h;
                out[r] *= __shfl(cor, src);
            }
        }
#pragma unroll
        for (int r = 0; r < 16; ++r) {
            sA[r] = __expf(sA[r] - m);
            sB[r] = __expf(sB[r] - m);
        }
        float ps = vsum16(sA) + vsum16(sB);
        ps += __shfl_xor(ps, 32);
        lsum += ps;

        const f16x8 pf0 = packP<0>(sA, h);
        const f16x8 pf1 = packP<8>(sA, h);
        const f16x8 pf2 = packP<0>(sB, h);
        const f16x8 pf3 = packP<8>(sB, h);
        const int vx = l31 & 7;
        const f16x8 vf0 = *(const f16x8*)&Vs[cur][l31 * 64 + ((h    ) ^ vx) * 8];
        const f16x8 vf1 = *(const f16x8*)&Vs[cur][l31 * 64 + ((2 + h) ^ vx) * 8];
        const f16x8 vf2 = *(const f16x8*)&Vs[cur][l31 * 64 + ((4 + h) ^ vx) * 8];
        const f16x8 vf3 = *(const f16x8*)&Vs[cur][l31 * 64 + ((6 + h) ^ vx) * 8];
        out = __builtin_amdgcn_mfma_f32_32x32x16_f16(pf0, vf0, out, 0, 0, 0);
        out = __builtin_amdgcn_mfma_f32_32x32x16_f16(pf1, vf1, out, 0, 0, 0);
        out = __builtin_amdgcn_mfma_f32_32x32x16_f16(pf2, vf2, out, 0, 0, 0);
        out = __builtin_amdgcn_mfma_f32_32x32x16_f16(pf3, vf3, out, 0, 0, 0);
        __syncthreads();
        cur ^= 1;
    }

    const float linv = 1.f / lsum;
    const int cOut = b * 256 + head * 32 + itile * 4 + w;
    u16* og = ao + (size_t)cOut * 1024 + l31;
#pragma unroll
    for (int r = 0; r < 16; ++r) {
        const int crow = (r & 3) + 8 * (r >> 2) + 4 * h;
        const float sc = __shfl(linv, crow);
        og[crow * 32] = f2h(out[r] * sc);
    }
}

// ---------------- OUT f16 MFMA GEMM: 64m x 64n, B from ao f16 ----------------
__global__ __launch_bounds__(256) void out_gemm_kernel(
    const u16* __restrict__ W, const u16* __restrict__ ao,
    const float* __restrict__ bias,
    const float* __restrict__ res, float* __restrict__ Y)
{
    __shared__ __align__(16) u16 sB[2][2048];
    const int b = blockIdx.z;
    const int m0 = blockIdx.y * 64, n0 = blockIdx.x * 64;
    const int t = threadIdx.x, w = t >> 6, lane = t & 63;
    const int l31 = lane & 31, h = lane >> 5;
    const int wm = w >> 1, wn = w & 1;
    const int msub = m0 + wm * 32;

    const u16* War = W + (size_t)(msub + l31) * 256 + h * 8;

    f32x16 acc;
#pragma unroll
    for (int r = 0; r < 16; ++r) {
        const int crow = (r & 3) + 8 * (r >> 2) + 4 * h;
        acc[r] = bias[msub + crow];
    }

    const int kL = t >> 3, pb = (t & 7) * 8;
    const u16* asrc = ao + ((size_t)b * 256 + kL) * 1024 + n0 + pb;
    u16x8 regs;

#define LOADC(kc) { regs = *(const u16x8*)(asrc + (size_t)(kc) * 32 * 1024); }
#define WRITEC(buf) { _Pragma("unroll") for (int e = 0; e < 8; ++e) { \
        const int n = pb + e; \
        const int idx = n * 32 + ((kL >> 3) ^ (n & 3)) * 8 + (kL & 7); \
        sB[buf][idx] = regs[e]; } }

    LOADC(0); WRITEC(0);
    __syncthreads();
    int cur = 0;
    for (int kc = 0; kc < 8; ++kc) {
        if (kc < 7) LOADC(kc + 1);
#pragma unroll
        for (int k16 = 0; k16 < 2; ++k16) {
            const f16x8 ah = *(const f16x8*)(War + kc * 32 + k16 * 16);
            const int gi = ((k16 * 2 + h) ^ (l31 & 3)) * 8;
            const int row = wn * 32 + l31;
            const f16x8 bh = *(const f16x8*)&sB[cur][row * 32 + gi];
            acc = __builtin_amdgcn_mfma_f32_32x32x16_f16(ah, bh, acc, 0, 0, 0);
        }
        if (kc < 7) WRITEC(cur ^ 1);
        __syncthreads();
        cur ^= 1;
    }
    const int n = n0 + wn * 32 + l31;
#pragma unroll
    for (int r = 0; r < 16; ++r) {
        const int mm = msub + (r & 3) + 8 * (r >> 2) + 4 * h;
        const size_t idx = ((size_t)b * 256 + mm) * 1024 + n;
        Y[idx] = acc[r] + res[idx];
    }
#undef LOADC
#undef WRITEC
}

extern "C" void kernel_launch(void* const* d_in, const int* in_sizes, int n_in,
                              void* d_out, int out_size, void* d_ws, size_t ws_size,
                              hipStream_t stream) {
    const float* x      = (const float*)d_in[0];
    const float* norm_w = (const float*)d_in[1];
    const float* norm_b = (const float*)d_in[2];
    const float* qkv_w  = (const float*)d_in[3];
    const float* qkv_b  = (const float*)d_in[4];
    const float* out_w  = (const float*)d_in[5];
    const float* out_b  = (const float*)d_in[6];
    float* out = (float*)d_out;

    char* p = (char*)d_ws;
    float2* stats = (float2*)p;  p += 4096;
    u16* XT  = (u16*)p;  p += 4u * 1024 * 1024;
    u16* Wq  = (u16*)p;  p += 393216 * 2;
    u16* Wo  = (u16*)p;  p += 131072 * 2;
    u16* qT  = (u16*)p;  p += 4u * 1024 * 1024;
    u16* kT  = (u16*)p;  p += 4u * 1024 * 1024;
    u16* vN  = (u16*)p;  p += 4u * 1024 * 1024;
    u16* ao  = (u16*)p;  p += 4u * 1024 * 1024;

    prep_kernel<<<512, 256, 0, stream>>>(x, qkv_w, out_w, stats, Wq, Wo);
    tsplit_kernel<<<dim3(16, 4, NB), 256, 0, stream>>>(x, stats, norm_w, norm_b, XT);
    qkv_gemm_kernel<<<dim3(16, 6, NB), 256, 0, stream>>>(Wq, XT, qkv_b, qT, kT, vN);
    attn_mfma_kernel<<<512, 256, 0, stream>>>(qT, kT, vN, ao);
    out_gemm_kernel<<<dim3(16, 4, NB), 256, 0, stream>>>(Wo, ao, out_b, x, out);
}